// Round 1
// baseline (793.021 us; speedup 1.0000x reference)
//
#include <hip/hip_runtime.h>

typedef __attribute__((ext_vector_type(8))) short short8;
typedef __attribute__((ext_vector_type(4))) float f32x4;

#define NB 2
#define SEQ 2048
#define DM 2048
#define NHEAD 16
#define HDIM 128

__device__ __forceinline__ unsigned short f2bf(float f) {
    unsigned u = __float_as_uint(f);
    u += 0x7fffu + ((u >> 16) & 1u);   // round-to-nearest-even (finite vals)
    return (unsigned short)(u >> 16);
}
__device__ __forceinline__ float bf2f(unsigned short h) {
    return __uint_as_float(((unsigned)h) << 16);
}

// C = A * B^T. A [M][K] row-major (f32 if ADT==0, bf16-as-u16 if ADT==1),
// B [Ncols][K] row-major f32. 128x128 tile, BK=32, 256 thr (4 waves, 2x2).
// EPI==0: plain f32 store to outf (ldc=2048). EPI==1: QKV scatter+layouts.
template<int ADT, int EPI>
__global__ __launch_bounds__(256) void gemm_bt(const void* __restrict__ Av,
                                               const float* __restrict__ Bf,
                                               int K,
                                               unsigned short* __restrict__ qb,
                                               unsigned short* __restrict__ kb,
                                               unsigned short* __restrict__ vtb,
                                               float* __restrict__ outf)
{
    __shared__ short At[2][128 * 32];
    __shared__ short Bt[2][128 * 32];
    const int tid = threadIdx.x;
    const int lane = tid & 63;
    const int w = tid >> 6;
    const int wr = w >> 1, wc = w & 1;
    const int g = lane >> 4, fr = lane & 15;
    const int row0 = blockIdx.y * 128, col0 = blockIdx.x * 128;
    const int sr = tid >> 2;            // staging row 0..63 (+64 for chunk 1)
    const int sc = (tid & 3) * 8;       // staging col 0/8/16/24

    const float* Afp = (const float*)Av;
    const unsigned short* Aup = (const unsigned short*)Av;

    const f32x4 fz = {0.f, 0.f, 0.f, 0.f};
    f32x4 acc[4][4];
#pragma unroll
    for (int m = 0; m < 4; ++m)
#pragma unroll
        for (int n = 0; n < 4; ++n) acc[m][n] = fz;

    f32x4 arf[2][2], brf[2][2];
    short8 aru[2];

    auto load_regs = [&](int kt) {
        int k0 = kt * 32;
#pragma unroll
        for (int i = 0; i < 2; ++i) {
            size_t ga = (size_t)(row0 + sr + i * 64) * K + k0 + sc;
            size_t gb = (size_t)(col0 + sr + i * 64) * K + k0 + sc;
            if constexpr (ADT == 0) {
                arf[i][0] = *(const f32x4*)(Afp + ga);
                arf[i][1] = *(const f32x4*)(Afp + ga + 4);
            } else {
                aru[i] = *(const short8*)(Aup + ga);
            }
            brf[i][0] = *(const f32x4*)(Bf + gb);
            brf[i][1] = *(const f32x4*)(Bf + gb + 4);
        }
    };
    auto write_lds = [&](int b) {
#pragma unroll
        for (int i = 0; i < 2; ++i) {
            short8 wv;
            if constexpr (ADT == 0) {
#pragma unroll
                for (int j = 0; j < 8; ++j) wv[j] = (short)f2bf(arf[i][j >> 2][j & 3]);
            } else {
                wv = aru[i];
            }
            *(short8*)&At[b][(sr + i * 64) * 32 + sc] = wv;
            short8 bv;
#pragma unroll
            for (int j = 0; j < 8; ++j) bv[j] = (short)f2bf(brf[i][j >> 2][j & 3]);
            *(short8*)&Bt[b][(sr + i * 64) * 32 + sc] = bv;
        }
    };

    const int nk = K / 32;
    load_regs(0);
    write_lds(0);
    __syncthreads();
    for (int kt = 0; kt < nk; ++kt) {
        const int cur = kt & 1;
        if (kt + 1 < nk) load_regs(kt + 1);
        short8 af[4], bfv[4];
#pragma unroll
        for (int m = 0; m < 4; ++m)
            af[m] = *(const short8*)&At[cur][(wr * 64 + m * 16 + fr) * 32 + g * 8];
#pragma unroll
        for (int n = 0; n < 4; ++n)
            bfv[n] = *(const short8*)&Bt[cur][(wc * 64 + n * 16 + fr) * 32 + g * 8];
#pragma unroll
        for (int m = 0; m < 4; ++m)
#pragma unroll
            for (int n = 0; n < 4; ++n)
                acc[m][n] = __builtin_amdgcn_mfma_f32_16x16x32_bf16(
                    af[m], bfv[n], acc[m][n], 0, 0, 0);
        __syncthreads();
        if (kt + 1 < nk) write_lds((kt + 1) & 1);
        __syncthreads();
    }

#pragma unroll
    for (int m = 0; m < 4; ++m)
#pragma unroll
        for (int n = 0; n < 4; ++n)
#pragma unroll
            for (int r = 0; r < 4; ++r) {
                int rr = row0 + wr * 64 + m * 16 + g * 4 + r;  // M index (D row)
                int cc = col0 + wc * 64 + n * 16 + fr;         // N index (D col)
                float val = acc[m][n][r];
                if constexpr (EPI == 0) {
                    outf[(size_t)rr * 2048 + cc] = val;
                } else {
                    int which = cc >> 11, h = (cc >> 7) & 15, hd = cc & 127;
                    int nb = rr >> 11, l = rr & 2047;
                    size_t hb = (size_t)(nb * NHEAD + h) * ((size_t)SEQ * HDIM);
                    unsigned short vb = f2bf(val);
                    if (which == 0)      qb[hb + (size_t)l * HDIM + hd] = vb;
                    else if (which == 1) kb[hb + (size_t)l * HDIM + hd] = vb;
                    else                 vtb[hb + (size_t)hd * SEQ + l] = vb;  // V^T
                }
            }
}

// in-place RoPE on [NB*NHEAD][SEQ][HDIM] bf16 buffer; pos = [2][SEQ][HDIM] f32
__global__ __launch_bounds__(256) void rope_k(unsigned short* __restrict__ t,
                                              const float* __restrict__ pos)
{
    size_t idx = (size_t)blockIdx.x * blockDim.x + threadIdx.x;
    if (idx >= (size_t)NB * NHEAD * SEQ * 64) return;
    int hd = idx & 63;
    int l = (idx >> 6) & (SEQ - 1);
    int nh = idx >> 17;
    size_t base = ((size_t)nh * SEQ + l) * HDIM;
    float x1 = bf2f(t[base + hd]);
    float x2 = bf2f(t[base + hd + 64]);
    const float* cp = pos + (size_t)l * HDIM;
    const float* sp = pos + (size_t)SEQ * HDIM + (size_t)l * HDIM;
    float c1 = cp[hd], s1 = sp[hd], c2 = cp[hd + 64], s2 = sp[hd + 64];
    t[base + hd]      = f2bf(x1 * c1 - x2 * s1);
    t[base + hd + 64] = f2bf(x2 * c2 + x1 * s2);
}

// causal flash attention. Q,K [nh][SEQ][HDIM], VT [nh][HDIM][SEQ] (all bf16),
// O [NB][SEQ][DM] bf16. 4 independent waves/block, 16 q-rows per wave, KV=32.
__global__ __launch_bounds__(256) void attn_k(const unsigned short* __restrict__ Q,
                                              const unsigned short* __restrict__ K,
                                              const unsigned short* __restrict__ VT,
                                              unsigned short* __restrict__ O)
{
    const int nh = blockIdx.y;
    const int qb4 = gridDim.x - 1 - blockIdx.x;  // heavy (long-loop) blocks first
    const int w = threadIdx.x >> 6, lane = threadIdx.x & 63;
    const int g = lane >> 4, fr = lane & 15;
    const int qt = qb4 * 64 + w * 16;
    const float scale = 0.08838834764831845f;  // 1/sqrt(128)

    const unsigned short* Qh = Q + (size_t)nh * SEQ * HDIM;
    const unsigned short* Kh = K + (size_t)nh * SEQ * HDIM;
    const unsigned short* Vh = VT + (size_t)nh * SEQ * HDIM;  // [128][SEQ]

    __shared__ unsigned short Plds[4][16 * 40];  // per-wave, stride 40 (80B, 16B-aligned)
    unsigned short* Pw = &Plds[w][0];

    // Q fragments: A-operand rows = q (fr), k = d contiguous
    short8 qf[4];
#pragma unroll
    for (int kk = 0; kk < 4; ++kk)
        qf[kk] = *(const short8*)(Qh + (size_t)(qt + fr) * HDIM + kk * 32 + g * 8);

    const f32x4 fz = {0.f, 0.f, 0.f, 0.f};
    f32x4 oacc[8];
#pragma unroll
    for (int f = 0; f < 8; ++f) oacc[f] = fz;
    float mrow[4] = {-3e38f, -3e38f, -3e38f, -3e38f};
    float lrow[4] = {0.f, 0.f, 0.f, 0.f};

    const int nkb = (qt + 15) / 32;  // inclusive upper block index
    for (int kb = 0; kb <= nkb; ++kb) {
        const int key0 = kb * 32;
        f32x4 s[2];
        s[0] = fz; s[1] = fz;
#pragma unroll
        for (int hh = 0; hh < 2; ++hh)
#pragma unroll
            for (int kk = 0; kk < 4; ++kk) {
                short8 kf = *(const short8*)(Kh + (size_t)(key0 + hh * 16 + fr) * HDIM + kk * 32 + g * 8);
                s[hh] = __builtin_amdgcn_mfma_f32_16x16x32_bf16(qf[kk], kf, s[hh], 0, 0, 0);
            }
        // scale + causal mask: D layout row=q=g*4+r, col=key=fr
#pragma unroll
        for (int hh = 0; hh < 2; ++hh)
#pragma unroll
            for (int r = 0; r < 4; ++r) {
                int key = key0 + hh * 16 + fr;
                int q = qt + g * 4 + r;
                float v = s[hh][r] * scale;
                s[hh][r] = (key <= q) ? v : -1e30f;
            }
        // row max across 16 lanes of the group
        float mx[4];
#pragma unroll
        for (int r = 0; r < 4; ++r) mx[r] = fmaxf(s[0][r], s[1][r]);
#pragma unroll
        for (int off = 1; off < 16; off <<= 1)
#pragma unroll
            for (int r = 0; r < 4; ++r) mx[r] = fmaxf(mx[r], __shfl_xor(mx[r], off, 64));
        float al[4];
#pragma unroll
        for (int r = 0; r < 4; ++r) {
            float mn = fmaxf(mrow[r], mx[r]);
            al[r] = __expf(mrow[r] - mn);
            mrow[r] = mn;
        }
        float ps[4] = {0.f, 0.f, 0.f, 0.f};
#pragma unroll
        for (int hh = 0; hh < 2; ++hh)
#pragma unroll
            for (int r = 0; r < 4; ++r) {
                float p = __expf(s[hh][r] - mrow[r]);
                s[hh][r] = p;
                ps[r] += p;
            }
#pragma unroll
        for (int off = 1; off < 16; off <<= 1)
#pragma unroll
            for (int r = 0; r < 4; ++r) ps[r] += __shfl_xor(ps[r], off, 64);
#pragma unroll
        for (int r = 0; r < 4; ++r) lrow[r] = lrow[r] * al[r] + ps[r];
#pragma unroll
        for (int f = 0; f < 8; ++f)
#pragma unroll
            for (int r = 0; r < 4; ++r) oacc[f][r] *= al[r];
        // P -> LDS (bf16), then re-read as PV A-fragment
#pragma unroll
        for (int hh = 0; hh < 2; ++hh)
#pragma unroll
            for (int r = 0; r < 4; ++r)
                Pw[(g * 4 + r) * 40 + hh * 16 + fr] = f2bf(s[hh][r]);
        asm volatile("s_waitcnt lgkmcnt(0)" ::: "memory");
        short8 pf = *(const short8*)(Pw + fr * 40 + g * 8);
#pragma unroll
        for (int f = 0; f < 8; ++f) {
            short8 vf = *(const short8*)(Vh + (size_t)(f * 16 + fr) * SEQ + key0 + g * 8);
            oacc[f] = __builtin_amdgcn_mfma_f32_16x16x32_bf16(pf, vf, oacc[f], 0, 0, 0);
        }
    }
    // epilogue: O[nb][l][h*128 + hd] bf16
    const int nb = nh >> 4, h = nh & 15;
#pragma unroll
    for (int f = 0; f < 8; ++f)
#pragma unroll
        for (int r = 0; r < 4; ++r) {
            int l = qt + g * 4 + r;
            float val = oacc[f][r] / lrow[r];
            O[((size_t)nb * SEQ + l) * DM + h * HDIM + f * 16 + fr] = f2bf(val);
        }
}

extern "C" void kernel_launch(void* const* d_in, const int* in_sizes, int n_in,
                              void* d_out, int out_size, void* d_ws, size_t ws_size,
                              hipStream_t stream) {
    const float* x    = (const float*)d_in[0];   // [2,2048,2048]
    const float* pos  = (const float*)d_in[1];   // [2,2048,128]
    const float* wqkv = (const float*)d_in[2];   // [6144,2048]
    const float* wo   = (const float*)d_in[3];   // [2048,2048]
    float* out = (float*)d_out;

    const size_t HBUF = (size_t)NB * NHEAD * SEQ * HDIM;  // 8Mi elems = 16MiB
    unsigned short* qb  = (unsigned short*)d_ws;
    unsigned short* kbuf = qb + HBUF;
    unsigned short* vtb = kbuf + HBUF;
    unsigned short* ob  = vtb + HBUF;

    // 1) QKV projection + scatter into head layouts (V transposed)
    gemm_bt<0, 1><<<dim3(48, 32), 256, 0, stream>>>(x, wqkv, 2048, qb, kbuf, vtb, nullptr);
    // 2) RoPE in-place on Q and K
    rope_k<<<dim3(16384), 256, 0, stream>>>(qb, pos);
    rope_k<<<dim3(16384), 256, 0, stream>>>(kbuf, pos);
    // 3) causal flash attention
    attn_k<<<dim3(SEQ / 64, NB * NHEAD), 256, 0, stream>>>(qb, kbuf, vtb, ob);
    // 4) output projection -> f32 d_out
    gemm_bt<1, 0><<<dim3(16, 32), 256, 0, stream>>>(ob, wo, 2048, nullptr, nullptr, nullptr, out);
}

// Round 2
// 506.274 us; speedup vs baseline: 1.5664x; 1.5664x over previous
//
#include <hip/hip_runtime.h>

typedef __attribute__((ext_vector_type(8))) short short8;
typedef __attribute__((ext_vector_type(4))) float f32x4;

#define NB 2
#define SEQ 2048
#define DM 2048
#define NHEAD 16
#define HDIM 128

__device__ __forceinline__ unsigned short f2bf(float f) {
    unsigned u = __float_as_uint(f);
    u += 0x7fffu + ((u >> 16) & 1u);   // round-to-nearest-even (finite vals)
    return (unsigned short)(u >> 16);
}
__device__ __forceinline__ float bf2f(unsigned short h) {
    return __uint_as_float(((unsigned)h) << 16);
}
__device__ __forceinline__ unsigned pk2bf(float a, float b) {
    return (unsigned)f2bf(a) | ((unsigned)f2bf(b) << 16);
}

// C = A * B^T. A [M][K] row-major (f32 if ADT==0, bf16-as-u16 if ADT==1),
// B [Ncols][K] row-major f32. 128x128 tile, BK=32, 256 thr (4 waves, 2x2).
// EPI==0: plain f32 store to outf (ldc=2048). EPI==1: QKV scatter+layouts.
template<int ADT, int EPI>
__global__ __launch_bounds__(256) void gemm_bt(const void* __restrict__ Av,
                                               const float* __restrict__ Bf,
                                               int K,
                                               unsigned short* __restrict__ qb,
                                               unsigned short* __restrict__ kb,
                                               unsigned short* __restrict__ vtb,
                                               float* __restrict__ outf)
{
    __shared__ short At[2][128 * 32];
    __shared__ short Bt[2][128 * 32];
    const int tid = threadIdx.x;
    const int lane = tid & 63;
    const int w = tid >> 6;
    const int wr = w >> 1, wc = w & 1;
    const int g = lane >> 4, fr = lane & 15;
    const int row0 = blockIdx.y * 128, col0 = blockIdx.x * 128;
    const int sr = tid >> 2;            // staging row 0..63 (+64 for chunk 1)
    const int sc = (tid & 3) * 8;       // staging col 0/8/16/24

    const float* Afp = (const float*)Av;
    const unsigned short* Aup = (const unsigned short*)Av;

    const f32x4 fz = {0.f, 0.f, 0.f, 0.f};
    f32x4 acc[4][4];
#pragma unroll
    for (int m = 0; m < 4; ++m)
#pragma unroll
        for (int n = 0; n < 4; ++n) acc[m][n] = fz;

    f32x4 arf[2][2], brf[2][2];
    short8 aru[2];

    auto load_regs = [&](int kt) {
        int k0 = kt * 32;
#pragma unroll
        for (int i = 0; i < 2; ++i) {
            size_t ga = (size_t)(row0 + sr + i * 64) * K + k0 + sc;
            size_t gb = (size_t)(col0 + sr + i * 64) * K + k0 + sc;
            if constexpr (ADT == 0) {
                arf[i][0] = *(const f32x4*)(Afp + ga);
                arf[i][1] = *(const f32x4*)(Afp + ga + 4);
            } else {
                aru[i] = *(const short8*)(Aup + ga);
            }
            brf[i][0] = *(const f32x4*)(Bf + gb);
            brf[i][1] = *(const f32x4*)(Bf + gb + 4);
        }
    };
    auto write_lds = [&](int b) {
#pragma unroll
        for (int i = 0; i < 2; ++i) {
            short8 wv;
            if constexpr (ADT == 0) {
#pragma unroll
                for (int j = 0; j < 8; ++j) wv[j] = (short)f2bf(arf[i][j >> 2][j & 3]);
            } else {
                wv = aru[i];
            }
            *(short8*)&At[b][(sr + i * 64) * 32 + sc] = wv;
            short8 bv;
#pragma unroll
            for (int j = 0; j < 8; ++j) bv[j] = (short)f2bf(brf[i][j >> 2][j & 3]);
            *(short8*)&Bt[b][(sr + i * 64) * 32 + sc] = bv;
        }
    };

    const int nk = K / 32;
    load_regs(0);
    write_lds(0);
    __syncthreads();
    for (int kt = 0; kt < nk; ++kt) {
        const int cur = kt & 1;
        if (kt + 1 < nk) load_regs(kt + 1);
        short8 af[4], bfv[4];
#pragma unroll
        for (int m = 0; m < 4; ++m)
            af[m] = *(const short8*)&At[cur][(wr * 64 + m * 16 + fr) * 32 + g * 8];
#pragma unroll
        for (int n = 0; n < 4; ++n)
            bfv[n] = *(const short8*)&Bt[cur][(wc * 64 + n * 16 + fr) * 32 + g * 8];
#pragma unroll
        for (int m = 0; m < 4; ++m)
#pragma unroll
            for (int n = 0; n < 4; ++n)
                acc[m][n] = __builtin_amdgcn_mfma_f32_16x16x32_bf16(
                    af[m], bfv[n], acc[m][n], 0, 0, 0);
        __syncthreads();
        if (kt + 1 < nk) write_lds((kt + 1) & 1);
        __syncthreads();
    }

#pragma unroll
    for (int m = 0; m < 4; ++m)
#pragma unroll
        for (int n = 0; n < 4; ++n)
#pragma unroll
            for (int r = 0; r < 4; ++r) {
                int rr = row0 + wr * 64 + m * 16 + g * 4 + r;  // M index (D row)
                int cc = col0 + wc * 64 + n * 16 + fr;         // N index (D col)
                float val = acc[m][n][r];
                if constexpr (EPI == 0) {
                    outf[(size_t)rr * 2048 + cc] = val;
                } else {
                    int which = cc >> 11, h = (cc >> 7) & 15, hd = cc & 127;
                    int nb = rr >> 11, l = rr & 2047;
                    size_t hb = (size_t)(nb * NHEAD + h) * ((size_t)SEQ * HDIM);
                    unsigned short vb = f2bf(val);
                    if (which == 0)      qb[hb + (size_t)l * HDIM + hd] = vb;
                    else if (which == 1) kb[hb + (size_t)l * HDIM + hd] = vb;
                    else                 vtb[hb + (size_t)hd * SEQ + l] = vb;  // V^T
                }
            }
}

// in-place RoPE on [NB*NHEAD][SEQ][HDIM] bf16 buffer; pos = [2][SEQ][HDIM] f32
__global__ __launch_bounds__(256) void rope_k(unsigned short* __restrict__ t,
                                              const float* __restrict__ pos)
{
    size_t idx = (size_t)blockIdx.x * blockDim.x + threadIdx.x;
    if (idx >= (size_t)NB * NHEAD * SEQ * 64) return;
    int hd = idx & 63;
    int l = (idx >> 6) & (SEQ - 1);
    int nh = idx >> 17;
    size_t base = ((size_t)nh * SEQ + l) * HDIM;
    float x1 = bf2f(t[base + hd]);
    float x2 = bf2f(t[base + hd + 64]);
    const float* cp = pos + (size_t)l * HDIM;
    const float* sp = pos + (size_t)SEQ * HDIM + (size_t)l * HDIM;
    float c1 = cp[hd], s1 = sp[hd], c2 = cp[hd + 64], s2 = sp[hd + 64];
    t[base + hd]      = f2bf(x1 * c1 - x2 * s1);
    t[base + hd + 64] = f2bf(x2 * c2 + x1 * s2);
}

// causal flash attention, swapped-QK^T form. Q,K [nh][SEQ][HDIM], VT
// [nh][HDIM][SEQ] (all bf16), O [NB][SEQ][DM] bf16.
// Block = 4 waves; wave handles 16 q-rows; block p does q-tiles p and 31-p
// (64 rows each) -> every block does exactly 68 KV-iterations (load balance).
// S^T = mfma(K,Q): lane (g,fr) holds S[key0+hh*16+4g+r][q=qt+fr] -> softmax
// row stats are in-lane + 2 shuffles. PV: O^T = mfma(V^T, P^T); the P^T
// B-fragment (lane fr holds P[q=fr][keys g*8..g*8+7]) is rebuilt via a small
// LDS bounce of packed bf16 pairs. K double-buffered in regs (prefetch).
__global__ __launch_bounds__(256) void attn_k(const unsigned short* __restrict__ Q,
                                              const unsigned short* __restrict__ K,
                                              const unsigned short* __restrict__ VT,
                                              unsigned short* __restrict__ O)
{
    const int nh = blockIdx.y;
    const int p = blockIdx.x;           // 0..15
    const int w = threadIdx.x >> 6, lane = threadIdx.x & 63;
    const int g = lane >> 4, fr = lane & 15;
    const float scale = 0.08838834764831845f;  // 1/sqrt(128)

    const unsigned short* Qh = Q + (size_t)nh * SEQ * HDIM;
    const unsigned short* Kh = K + (size_t)nh * SEQ * HDIM;
    const unsigned short* Vh = VT + (size_t)nh * SEQ * HDIM;  // [128][SEQ]
    const int nb = nh >> 4, h = nh & 15;

    __shared__ unsigned Plds[4][16 * 20];  // per-wave P^T bounce, row stride 20 u32 (80B)
    unsigned* Pw = &Plds[w][0];

    for (int pass = 0; pass < 2; ++pass) {
        const int tile = pass ? (31 - p) : p;
        const int qt = tile * 64 + w * 16;

        short8 qf[4];
#pragma unroll
        for (int kk = 0; kk < 4; ++kk)
            qf[kk] = *(const short8*)(Qh + (size_t)(qt + fr) * HDIM + kk * 32 + g * 8);

        const f32x4 fz = {0.f, 0.f, 0.f, 0.f};
        f32x4 oacc[8];
#pragma unroll
        for (int f = 0; f < 8; ++f) oacc[f] = fz;
        float mrow = -3e38f, lrow = 0.f;

        const int nkb = (qt + 15) >> 5;  // inclusive upper KV-block index

        short8 kA[2][4], kB[2][4];
        auto loadK = [&](short8 (&dst)[2][4], int kbi) {
            const int key0 = kbi * 32;
#pragma unroll
            for (int hh = 0; hh < 2; ++hh)
#pragma unroll
                for (int kk = 0; kk < 4; ++kk)
                    dst[hh][kk] = *(const short8*)(Kh + (size_t)(key0 + hh * 16 + fr) * HDIM + kk * 32 + g * 8);
        };

        auto body = [&](short8 (&cur)[2][4], short8 (&nxt)[2][4], int kbi) {
            const int key0 = kbi * 32;
            // V loads early: latency hides under QK^T + softmax
            short8 vf[8];
#pragma unroll
            for (int f = 0; f < 8; ++f)
                vf[f] = *(const short8*)(Vh + (size_t)(f * 16 + fr) * SEQ + key0 + g * 8);
            // prefetch next K tile
            if (kbi < nkb) loadK(nxt, kbi + 1);

            f32x4 s[2];
            s[0] = fz; s[1] = fz;
            __builtin_amdgcn_s_setprio(1);
#pragma unroll
            for (int hh = 0; hh < 2; ++hh)
#pragma unroll
                for (int kk = 0; kk < 4; ++kk)
                    s[hh] = __builtin_amdgcn_mfma_f32_16x16x32_bf16(cur[hh][kk], qf[kk], s[hh], 0, 0, 0);
            __builtin_amdgcn_s_setprio(0);

            // scale + causal mask; lane's q = qt+fr, keys = key0+hh*16+4g+r
            const int q = qt + fr;
#pragma unroll
            for (int hh = 0; hh < 2; ++hh)
#pragma unroll
                for (int r = 0; r < 4; ++r) {
                    int key = key0 + hh * 16 + 4 * g + r;
                    float v = s[hh][r] * scale;
                    s[hh][r] = (key <= q) ? v : -1e30f;
                }
            // row max: 7 in-lane + 2 shuffles (across g)
            float mx = fmaxf(fmaxf(fmaxf(s[0][0], s[0][1]), fmaxf(s[0][2], s[0][3])),
                             fmaxf(fmaxf(s[1][0], s[1][1]), fmaxf(s[1][2], s[1][3])));
            mx = fmaxf(mx, __shfl_xor(mx, 16, 64));
            mx = fmaxf(mx, __shfl_xor(mx, 32, 64));
            float mn = fmaxf(mrow, mx);
            float al = __expf(mrow - mn);
            mrow = mn;
            float pv[2][4];
            float ps = 0.f;
#pragma unroll
            for (int hh = 0; hh < 2; ++hh)
#pragma unroll
                for (int r = 0; r < 4; ++r) {
                    float e = __expf(s[hh][r] - mn);
                    pv[hh][r] = e;
                    ps += e;
                }
            ps += __shfl_xor(ps, 16, 64);
            ps += __shfl_xor(ps, 32, 64);
            lrow = lrow * al + ps;
#pragma unroll
            for (int f = 0; f < 8; ++f)
#pragma unroll
                for (int r = 0; r < 4; ++r) oacc[f][r] *= al;

            // P^T bounce: lane (g,fr) holds P[q=fr][16hh+4g+r]; word kw holds
            // keys {2kw,2kw+1}; write words 8hh+2g+c, read words 4g..4g+3.
#pragma unroll
            for (int hh = 0; hh < 2; ++hh) {
                Pw[fr * 20 + hh * 8 + 2 * g + 0] = pk2bf(pv[hh][0], pv[hh][1]);
                Pw[fr * 20 + hh * 8 + 2 * g + 1] = pk2bf(pv[hh][2], pv[hh][3]);
            }
            asm volatile("s_waitcnt lgkmcnt(0)" ::: "memory");
            short8 pf = *(const short8*)&Pw[fr * 20 + g * 4];

            __builtin_amdgcn_s_setprio(1);
#pragma unroll
            for (int f = 0; f < 8; ++f)
                oacc[f] = __builtin_amdgcn_mfma_f32_16x16x32_bf16(vf[f], pf, oacc[f], 0, 0, 0);
            __builtin_amdgcn_s_setprio(0);
        };

        loadK(kA, 0);
        int kbi = 0;
        while (true) {
            body(kA, kB, kbi);
            if (++kbi > nkb) break;
            body(kB, kA, kbi);
            if (++kbi > nkb) break;
        }

        // epilogue: O^T layout -> lane (g,fr): q = qt+fr, d = f*16+4g+r
        const float inv = 1.0f / lrow;
        const size_t obase = ((size_t)nb * SEQ + qt + fr) * DM + h * HDIM;
#pragma unroll
        for (int f = 0; f < 8; ++f) {
            unsigned w0 = pk2bf(oacc[f][0] * inv, oacc[f][1] * inv);
            unsigned w1 = pk2bf(oacc[f][2] * inv, oacc[f][3] * inv);
            unsigned* dst = (unsigned*)(O + obase + f * 16 + 4 * g);
            dst[0] = w0;
            dst[1] = w1;
        }
    }
}

extern "C" void kernel_launch(void* const* d_in, const int* in_sizes, int n_in,
                              void* d_out, int out_size, void* d_ws, size_t ws_size,
                              hipStream_t stream) {
    const float* x    = (const float*)d_in[0];   // [2,2048,2048]
    const float* pos  = (const float*)d_in[1];   // [2,2048,128]
    const float* wqkv = (const float*)d_in[2];   // [6144,2048]
    const float* wo   = (const float*)d_in[3];   // [2048,2048]
    float* out = (float*)d_out;

    const size_t HBUF = (size_t)NB * NHEAD * SEQ * HDIM;  // 8Mi elems = 16MiB
    unsigned short* qb  = (unsigned short*)d_ws;
    unsigned short* kbuf = qb + HBUF;
    unsigned short* vtb = kbuf + HBUF;
    unsigned short* ob  = vtb + HBUF;

    // 1) QKV projection + scatter into head layouts (V transposed)
    gemm_bt<0, 1><<<dim3(48, 32), 256, 0, stream>>>(x, wqkv, 2048, qb, kbuf, vtb, nullptr);
    // 2) RoPE in-place on Q and K
    rope_k<<<dim3(16384), 256, 0, stream>>>(qb, pos);
    rope_k<<<dim3(16384), 256, 0, stream>>>(kbuf, pos);
    // 3) causal flash attention (swapped-QK, balanced blocks)
    attn_k<<<dim3(16, NB * NHEAD), 256, 0, stream>>>(qb, kbuf, vtb, ob);
    // 4) output projection -> f32 d_out
    gemm_bt<1, 0><<<dim3(16, 32), 256, 0, stream>>>(ob, wo, 2048, nullptr, nullptr, nullptr, out);
}

// Round 3
// 492.265 us; speedup vs baseline: 1.6110x; 1.0285x over previous
//
#include <hip/hip_runtime.h>

typedef __attribute__((ext_vector_type(8))) short short8;
typedef __attribute__((ext_vector_type(4))) float f32x4;

#define NB 2
#define SEQ 2048
#define DM 2048
#define NHEAD 16
#define HDIM 128

__device__ __forceinline__ unsigned short f2bf(float f) {
    unsigned u = __float_as_uint(f);
    u += 0x7fffu + ((u >> 16) & 1u);   // round-to-nearest-even (finite vals)
    return (unsigned short)(u >> 16);
}
__device__ __forceinline__ float bf2f(unsigned short h) {
    return __uint_as_float(((unsigned)h) << 16);
}
__device__ __forceinline__ unsigned pk2bf(float a, float b) {
    return (unsigned)f2bf(a) | ((unsigned)f2bf(b) << 16);
}

// C = A * B^T. A [M][K] row-major (f32 if ADT==0, bf16-as-u16 if ADT==1),
// B [Ncols][K] row-major f32. 128x128 tile, BK=32, 256 thr (4 waves, 2x2).
// EPI==0: plain f32 store to outf (ldc=2048).
// EPI==1: QKV scatter+layouts, with RoPE fused for Q/K blocks (each block
//         covers exactly one (which,head) 128-col span; hd pairs exchanged
//         through the re-used 32KB staging LDS).
template<int ADT, int EPI>
__global__ __launch_bounds__(256) void gemm_bt(const void* __restrict__ Av,
                                               const float* __restrict__ Bf,
                                               int K,
                                               unsigned short* __restrict__ qb,
                                               unsigned short* __restrict__ kb,
                                               unsigned short* __restrict__ vtb,
                                               float* __restrict__ outf,
                                               const float* __restrict__ posp)
{
    __shared__ short smem[16384];   // staging: At=[0,8192) Bt=[8192,16384); epilogue: [128][128] bf16
#define AT_(b) (smem + (b) * 4096)
#define BT_(b) (smem + 8192 + (b) * 4096)
    const int tid = threadIdx.x;
    const int lane = tid & 63;
    const int w = tid >> 6;
    const int wr = w >> 1, wc = w & 1;
    const int g = lane >> 4, fr = lane & 15;
    const int row0 = blockIdx.y * 128, col0 = blockIdx.x * 128;
    const int sr = tid >> 2;            // staging row 0..63 (+64 for chunk 1)
    const int sc = (tid & 3) * 8;       // staging col 0/8/16/24

    const float* Afp = (const float*)Av;
    const unsigned short* Aup = (const unsigned short*)Av;

    const f32x4 fz = {0.f, 0.f, 0.f, 0.f};
    f32x4 acc[4][4];
#pragma unroll
    for (int m = 0; m < 4; ++m)
#pragma unroll
        for (int n = 0; n < 4; ++n) acc[m][n] = fz;

    f32x4 arf[2][2], brf[2][2];
    short8 aru[2];

    auto load_regs = [&](int kt) {
        int k0 = kt * 32;
#pragma unroll
        for (int i = 0; i < 2; ++i) {
            size_t ga = (size_t)(row0 + sr + i * 64) * K + k0 + sc;
            size_t gb = (size_t)(col0 + sr + i * 64) * K + k0 + sc;
            if constexpr (ADT == 0) {
                arf[i][0] = *(const f32x4*)(Afp + ga);
                arf[i][1] = *(const f32x4*)(Afp + ga + 4);
            } else {
                aru[i] = *(const short8*)(Aup + ga);
            }
            brf[i][0] = *(const f32x4*)(Bf + gb);
            brf[i][1] = *(const f32x4*)(Bf + gb + 4);
        }
    };
    auto write_lds = [&](int b) {
#pragma unroll
        for (int i = 0; i < 2; ++i) {
            short8 wv;
            if constexpr (ADT == 0) {
#pragma unroll
                for (int j = 0; j < 8; ++j) wv[j] = (short)f2bf(arf[i][j >> 2][j & 3]);
            } else {
                wv = aru[i];
            }
            *(short8*)&AT_(b)[(sr + i * 64) * 32 + sc] = wv;
            short8 bv;
#pragma unroll
            for (int j = 0; j < 8; ++j) bv[j] = (short)f2bf(brf[i][j >> 2][j & 3]);
            *(short8*)&BT_(b)[(sr + i * 64) * 32 + sc] = bv;
        }
    };

    const int nk = K / 32;
    load_regs(0);
    write_lds(0);
    __syncthreads();
    for (int kt = 0; kt < nk; ++kt) {
        const int cur = kt & 1;
        if (kt + 1 < nk) load_regs(kt + 1);
        short8 af[4], bfv[4];
#pragma unroll
        for (int m = 0; m < 4; ++m)
            af[m] = *(const short8*)&AT_(cur)[(wr * 64 + m * 16 + fr) * 32 + g * 8];
#pragma unroll
        for (int n = 0; n < 4; ++n)
            bfv[n] = *(const short8*)&BT_(cur)[(wc * 64 + n * 16 + fr) * 32 + g * 8];
#pragma unroll
        for (int m = 0; m < 4; ++m)
#pragma unroll
            for (int n = 0; n < 4; ++n)
                acc[m][n] = __builtin_amdgcn_mfma_f32_16x16x32_bf16(
                    af[m], bfv[n], acc[m][n], 0, 0, 0);
        __syncthreads();
        if (kt + 1 < nk) write_lds((kt + 1) & 1);
        __syncthreads();
    }

    if constexpr (EPI == 0) {
#pragma unroll
        for (int m = 0; m < 4; ++m)
#pragma unroll
            for (int n = 0; n < 4; ++n)
#pragma unroll
                for (int r = 0; r < 4; ++r) {
                    int rr = row0 + wr * 64 + m * 16 + g * 4 + r;
                    int cc = col0 + wc * 64 + n * 16 + fr;
                    outf[(size_t)rr * 2048 + cc] = acc[m][n][r];
                }
    } else {
        const int which = col0 >> 11;        // 0=Q 1=K 2=V (uniform per block)
        const int hB = (col0 >> 7) & 15;     // head (uniform per block)
        if (which < 2) {
            // stash whole C-tile as bf16 into smem[128][128] for pair exchange
#pragma unroll
            for (int m = 0; m < 4; ++m)
#pragma unroll
                for (int n = 0; n < 4; ++n)
#pragma unroll
                    for (int r = 0; r < 4; ++r) {
                        int rl = wr * 64 + m * 16 + g * 4 + r;
                        int cl = wc * 64 + n * 16 + fr;
                        smem[rl * 128 + cl] = (short)f2bf(acc[m][n][r]);
                    }
            __syncthreads();
            unsigned short* dst = which ? kb : qb;
#pragma unroll
            for (int m = 0; m < 4; ++m)
#pragma unroll
                for (int n = 0; n < 4; ++n)
#pragma unroll
                    for (int r = 0; r < 4; ++r) {
                        int rl = wr * 64 + m * 16 + g * 4 + r;
                        int cl = wc * 64 + n * 16 + fr;
                        int rr = row0 + rl;
                        int l = rr & 2047, nb_ = rr >> 11;
                        float own = acc[m][n][r];
                        float pr = bf2f((unsigned short)smem[rl * 128 + (cl ^ 64)]);
                        float c = posp[(size_t)l * HDIM + cl];
                        float s = posp[(size_t)SEQ * HDIM + (size_t)l * HDIM + cl];
                        float res = (cl < 64) ? (own * c - pr * s) : (own * c + pr * s);
                        size_t hb = (size_t)(nb_ * NHEAD + hB) * ((size_t)SEQ * HDIM);
                        dst[hb + (size_t)l * HDIM + cl] = f2bf(res);
                    }
        } else {
#pragma unroll
            for (int m = 0; m < 4; ++m)
#pragma unroll
                for (int n = 0; n < 4; ++n)
#pragma unroll
                    for (int r = 0; r < 4; ++r) {
                        int rr = row0 + wr * 64 + m * 16 + g * 4 + r;
                        int cl = wc * 64 + n * 16 + fr;   // hd
                        int l = rr & 2047, nb_ = rr >> 11;
                        size_t hb = (size_t)(nb_ * NHEAD + hB) * ((size_t)SEQ * HDIM);
                        vtb[hb + (size_t)cl * SEQ + l] = f2bf(acc[m][n][r]);  // V^T
                    }
        }
    }
#undef AT_
#undef BT_
}

// causal flash attention, swapped-QK^T form, 32 q-rows/wave.
// Q,K [nh][SEQ][HDIM], VT [nh][HDIM][SEQ] (all bf16), O [NB][SEQ][DM] bf16.
// 1-D grid of 512; block l -> XCD l%8; XCD x owns heads 4x..4x+3 (K/V
// working set 4MB = L2-resident). Block p does q-tiles p and 15-p (128 rows
// each, 4 waves x 32 rows) -> every block ~68 KV-iterations (balanced).
// S^T = mfma(K,Q): lane (g,fr) holds S[key0+16hh+4g+r][q=qt+16u+fr].
// PV: O^T = mfma(V^T, P^T); P^T B-fragment rebuilt via per-wave LDS bounce.
__global__ __launch_bounds__(256, 2) void attn_k(const unsigned short* __restrict__ Q,
                                                 const unsigned short* __restrict__ K,
                                                 const unsigned short* __restrict__ VT,
                                                 unsigned short* __restrict__ O)
{
    const int lb = blockIdx.x;            // 0..511
    const int xcd = lb & 7, idx = lb >> 3;
    const int nh = xcd * 4 + (idx >> 4);  // heads grouped per XCD
    const int p = idx & 15;
    const int w = threadIdx.x >> 6, lane = threadIdx.x & 63;
    const int g = lane >> 4, fr = lane & 15;
    const float scale = 0.08838834764831845f;  // 1/sqrt(128)

    const unsigned short* Qh = Q + (size_t)nh * SEQ * HDIM;
    const unsigned short* Kh = K + (size_t)nh * SEQ * HDIM;
    const unsigned short* Vh = VT + (size_t)nh * SEQ * HDIM;  // [128][SEQ]
    const int nb = nh >> 4, h = nh & 15;

    __shared__ unsigned Plds[4][2][320];  // per-wave, per-u; row stride 20 u32 (80B)

    for (int pass = 0; pass < 2; ++pass) {
        const int tile = pass ? (15 - p) : p;
        const int qt = tile * 128 + w * 32;

        short8 qf[2][4];
#pragma unroll
        for (int u = 0; u < 2; ++u)
#pragma unroll
            for (int kk = 0; kk < 4; ++kk)
                qf[u][kk] = *(const short8*)(Qh + (size_t)(qt + u * 16 + fr) * HDIM + kk * 32 + g * 8);

        const f32x4 fz = {0.f, 0.f, 0.f, 0.f};
        f32x4 oacc[2][8];
#pragma unroll
        for (int u = 0; u < 2; ++u)
#pragma unroll
            for (int f = 0; f < 8; ++f) oacc[u][f] = fz;
        float mrow[2] = {-3e38f, -3e38f}, lrow[2] = {0.f, 0.f};

        const int nkb = (qt + 31) >> 5;  // inclusive upper KV-block index

        for (int kbi = 0; kbi <= nkb; ++kbi) {
            const int key0 = kbi * 32;
            // V loads early: latency hides under K-load + QK^T + softmax
            short8 vf[8];
#pragma unroll
            for (int f = 0; f < 8; ++f)
                vf[f] = *(const short8*)(Vh + (size_t)(f * 16 + fr) * SEQ + key0 + g * 8);
            short8 kf[2][4];
#pragma unroll
            for (int hh = 0; hh < 2; ++hh)
#pragma unroll
                for (int kk = 0; kk < 4; ++kk)
                    kf[hh][kk] = *(const short8*)(Kh + (size_t)(key0 + hh * 16 + fr) * HDIM + kk * 32 + g * 8);

            f32x4 s[2][2];
#pragma unroll
            for (int u = 0; u < 2; ++u) { s[u][0] = fz; s[u][1] = fz; }
            __builtin_amdgcn_s_setprio(1);
#pragma unroll
            for (int u = 0; u < 2; ++u)
#pragma unroll
                for (int hh = 0; hh < 2; ++hh)
#pragma unroll
                    for (int kk = 0; kk < 4; ++kk)
                        s[u][hh] = __builtin_amdgcn_mfma_f32_16x16x32_bf16(kf[hh][kk], qf[u][kk], s[u][hh], 0, 0, 0);
            __builtin_amdgcn_s_setprio(0);

#pragma unroll
            for (int u = 0; u < 2; ++u) {
                const int q = qt + u * 16 + fr;
#pragma unroll
                for (int hh = 0; hh < 2; ++hh)
#pragma unroll
                    for (int r = 0; r < 4; ++r) {
                        int key = key0 + hh * 16 + 4 * g + r;
                        float v = s[u][hh][r] * scale;
                        s[u][hh][r] = (key <= q) ? v : -1e30f;
                    }
                float mx = fmaxf(fmaxf(fmaxf(s[u][0][0], s[u][0][1]), fmaxf(s[u][0][2], s[u][0][3])),
                                 fmaxf(fmaxf(s[u][1][0], s[u][1][1]), fmaxf(s[u][1][2], s[u][1][3])));
                mx = fmaxf(mx, __shfl_xor(mx, 16, 64));
                mx = fmaxf(mx, __shfl_xor(mx, 32, 64));
                float mn = fmaxf(mrow[u], mx);
                float al = __expf(mrow[u] - mn);
                mrow[u] = mn;
                float pv[2][4];
                float ps = 0.f;
#pragma unroll
                for (int hh = 0; hh < 2; ++hh)
#pragma unroll
                    for (int r = 0; r < 4; ++r) {
                        float e = __expf(s[u][hh][r] - mn);
                        pv[hh][r] = e;
                        ps += e;
                    }
                ps += __shfl_xor(ps, 16, 64);
                ps += __shfl_xor(ps, 32, 64);
                lrow[u] = lrow[u] * al + ps;
#pragma unroll
                for (int f = 0; f < 8; ++f)
#pragma unroll
                    for (int r = 0; r < 4; ++r) oacc[u][f][r] *= al;
                // P^T bounce: word kw holds keys {2kw,2kw+1}
                unsigned* Pw = &Plds[w][u][0];
#pragma unroll
                for (int hh = 0; hh < 2; ++hh) {
                    Pw[fr * 20 + hh * 8 + 2 * g + 0] = pk2bf(pv[hh][0], pv[hh][1]);
                    Pw[fr * 20 + hh * 8 + 2 * g + 1] = pk2bf(pv[hh][2], pv[hh][3]);
                }
            }
            asm volatile("s_waitcnt lgkmcnt(0)" ::: "memory");
            short8 pf[2];
#pragma unroll
            for (int u = 0; u < 2; ++u)
                pf[u] = *(const short8*)&Plds[w][u][fr * 20 + g * 4];

            __builtin_amdgcn_s_setprio(1);
#pragma unroll
            for (int u = 0; u < 2; ++u)
#pragma unroll
                for (int f = 0; f < 8; ++f)
                    oacc[u][f] = __builtin_amdgcn_mfma_f32_16x16x32_bf16(vf[f], pf[u], oacc[u][f], 0, 0, 0);
            __builtin_amdgcn_s_setprio(0);
        }

        // epilogue: O^T layout -> lane (g,fr): q = qt+16u+fr, d = f*16+4g+r
#pragma unroll
        for (int u = 0; u < 2; ++u) {
            const float inv = 1.0f / lrow[u];
            const size_t obase = ((size_t)nb * SEQ + qt + u * 16 + fr) * DM + h * HDIM;
#pragma unroll
            for (int f = 0; f < 8; ++f) {
                unsigned w0 = pk2bf(oacc[u][f][0] * inv, oacc[u][f][1] * inv);
                unsigned w1 = pk2bf(oacc[u][f][2] * inv, oacc[u][f][3] * inv);
                unsigned* dstp = (unsigned*)(O + obase + f * 16 + 4 * g);
                dstp[0] = w0;
                dstp[1] = w1;
            }
        }
    }
}

extern "C" void kernel_launch(void* const* d_in, const int* in_sizes, int n_in,
                              void* d_out, int out_size, void* d_ws, size_t ws_size,
                              hipStream_t stream) {
    const float* x    = (const float*)d_in[0];   // [2,2048,2048]
    const float* pos  = (const float*)d_in[1];   // [2,2048,128]
    const float* wqkv = (const float*)d_in[2];   // [6144,2048]
    const float* wo   = (const float*)d_in[3];   // [2048,2048]
    float* out = (float*)d_out;

    const size_t HBUF = (size_t)NB * NHEAD * SEQ * HDIM;  // 8Mi elems = 16MiB
    unsigned short* qb  = (unsigned short*)d_ws;
    unsigned short* kbuf = qb + HBUF;
    unsigned short* vtb = kbuf + HBUF;
    unsigned short* ob  = vtb + HBUF;

    // 1) QKV projection + RoPE(Q,K) + scatter into head layouts (V transposed)
    gemm_bt<0, 1><<<dim3(48, 32), 256, 0, stream>>>(x, wqkv, 2048, qb, kbuf, vtb, nullptr, pos);
    // 2) causal flash attention (swapped-QK, XCD head grouping, balanced)
    attn_k<<<dim3(512), 256, 0, stream>>>(qb, kbuf, vtb, ob);
    // 3) output projection -> f32 d_out
    gemm_bt<1, 0><<<dim3(16, 32), 256, 0, stream>>>(ob, wo, 2048, nullptr, nullptr, nullptr, out, nullptr);
}

// Round 4
// 388.939 us; speedup vs baseline: 2.0389x; 1.2657x over previous
//
#include <hip/hip_runtime.h>

typedef __attribute__((ext_vector_type(8))) short short8;
typedef __attribute__((ext_vector_type(4))) float f32x4;

#define NB 2
#define SEQ 2048
#define DM 2048
#define NHEAD 16
#define HDIM 128

__device__ __forceinline__ unsigned short f2bf(float f) {
    unsigned u = __float_as_uint(f);
    u += 0x7fffu + ((u >> 16) & 1u);   // round-to-nearest-even (finite vals)
    return (unsigned short)(u >> 16);
}
__device__ __forceinline__ float bf2f(unsigned short h) {
    return __uint_as_float(((unsigned)h) << 16);
}
__device__ __forceinline__ unsigned pk2bf(float a, float b) {
    return (unsigned)f2bf(a) | ((unsigned)f2bf(b) << 16);
}
// async global->LDS, 16B per lane. LDS dest must be wave-uniform base;
// HW writes base + lane*16. Global src is per-lane.
__device__ __forceinline__ void gload16(const unsigned short* g, unsigned short* l) {
    __builtin_amdgcn_global_load_lds((const __attribute__((address_space(1))) void*)g,
                                     (__attribute__((address_space(3))) void*)l,
                                     16, 0, 0);
}

// C = A * B^T. A [M][K] row-major (f32 if ADT==0, bf16-as-u16 if ADT==1),
// B [Ncols][K] row-major f32. 128x128 tile, BK=32, 256 thr (4 waves, 2x2).
// EPI==0: plain f32 store to outf (ldc=2048).
// EPI==1: QKV scatter+layouts, with RoPE fused for Q/K blocks.
template<int ADT, int EPI>
__global__ __launch_bounds__(256) void gemm_bt(const void* __restrict__ Av,
                                               const float* __restrict__ Bf,
                                               int K,
                                               unsigned short* __restrict__ qb,
                                               unsigned short* __restrict__ kb,
                                               unsigned short* __restrict__ vtb,
                                               float* __restrict__ outf,
                                               const float* __restrict__ posp)
{
    __shared__ short smem[16384];   // staging: At=[0,8192) Bt=[8192,16384); epilogue: [128][128] bf16
#define AT_(b) (smem + (b) * 4096)
#define BT_(b) (smem + 8192 + (b) * 4096)
    const int tid = threadIdx.x;
    const int lane = tid & 63;
    const int w = tid >> 6;
    const int wr = w >> 1, wc = w & 1;
    const int g = lane >> 4, fr = lane & 15;
    const int row0 = blockIdx.y * 128, col0 = blockIdx.x * 128;
    const int sr = tid >> 2;            // staging row 0..63 (+64 for chunk 1)
    const int sc = (tid & 3) * 8;       // staging col 0/8/16/24

    const float* Afp = (const float*)Av;
    const unsigned short* Aup = (const unsigned short*)Av;

    const f32x4 fz = {0.f, 0.f, 0.f, 0.f};
    f32x4 acc[4][4];
#pragma unroll
    for (int m = 0; m < 4; ++m)
#pragma unroll
        for (int n = 0; n < 4; ++n) acc[m][n] = fz;

    f32x4 arf[2][2], brf[2][2];
    short8 aru[2];

    auto load_regs = [&](int kt) {
        int k0 = kt * 32;
#pragma unroll
        for (int i = 0; i < 2; ++i) {
            size_t ga = (size_t)(row0 + sr + i * 64) * K + k0 + sc;
            size_t gb = (size_t)(col0 + sr + i * 64) * K + k0 + sc;
            if constexpr (ADT == 0) {
                arf[i][0] = *(const f32x4*)(Afp + ga);
                arf[i][1] = *(const f32x4*)(Afp + ga + 4);
            } else {
                aru[i] = *(const short8*)(Aup + ga);
            }
            brf[i][0] = *(const f32x4*)(Bf + gb);
            brf[i][1] = *(const f32x4*)(Bf + gb + 4);
        }
    };
    auto write_lds = [&](int b) {
#pragma unroll
        for (int i = 0; i < 2; ++i) {
            short8 wv;
            if constexpr (ADT == 0) {
#pragma unroll
                for (int j = 0; j < 8; ++j) wv[j] = (short)f2bf(arf[i][j >> 2][j & 3]);
            } else {
                wv = aru[i];
            }
            *(short8*)&AT_(b)[(sr + i * 64) * 32 + sc] = wv;
            short8 bv;
#pragma unroll
            for (int j = 0; j < 8; ++j) bv[j] = (short)f2bf(brf[i][j >> 2][j & 3]);
            *(short8*)&BT_(b)[(sr + i * 64) * 32 + sc] = bv;
        }
    };

    const int nk = K / 32;
    load_regs(0);
    write_lds(0);
    __syncthreads();
    for (int kt = 0; kt < nk; ++kt) {
        const int cur = kt & 1;
        if (kt + 1 < nk) load_regs(kt + 1);
        short8 af[4], bfv[4];
#pragma unroll
        for (int m = 0; m < 4; ++m)
            af[m] = *(const short8*)&AT_(cur)[(wr * 64 + m * 16 + fr) * 32 + g * 8];
#pragma unroll
        for (int n = 0; n < 4; ++n)
            bfv[n] = *(const short8*)&BT_(cur)[(wc * 64 + n * 16 + fr) * 32 + g * 8];
#pragma unroll
        for (int m = 0; m < 4; ++m)
#pragma unroll
            for (int n = 0; n < 4; ++n)
                acc[m][n] = __builtin_amdgcn_mfma_f32_16x16x32_bf16(
                    af[m], bfv[n], acc[m][n], 0, 0, 0);
        __syncthreads();
        if (kt + 1 < nk) write_lds((kt + 1) & 1);
        __syncthreads();
    }

    if constexpr (EPI == 0) {
#pragma unroll
        for (int m = 0; m < 4; ++m)
#pragma unroll
            for (int n = 0; n < 4; ++n)
#pragma unroll
                for (int r = 0; r < 4; ++r) {
                    int rr = row0 + wr * 64 + m * 16 + g * 4 + r;
                    int cc = col0 + wc * 64 + n * 16 + fr;
                    outf[(size_t)rr * 2048 + cc] = acc[m][n][r];
                }
    } else {
        const int which = col0 >> 11;        // 0=Q 1=K 2=V (uniform per block)
        const int hB = (col0 >> 7) & 15;     // head (uniform per block)
        if (which < 2) {
            // stash whole C-tile as bf16 into smem[128][128] for pair exchange
#pragma unroll
            for (int m = 0; m < 4; ++m)
#pragma unroll
                for (int n = 0; n < 4; ++n)
#pragma unroll
                    for (int r = 0; r < 4; ++r) {
                        int rl = wr * 64 + m * 16 + g * 4 + r;
                        int cl = wc * 64 + n * 16 + fr;
                        smem[rl * 128 + cl] = (short)f2bf(acc[m][n][r]);
                    }
            __syncthreads();
            unsigned short* dst = which ? kb : qb;
#pragma unroll
            for (int m = 0; m < 4; ++m)
#pragma unroll
                for (int n = 0; n < 4; ++n)
#pragma unroll
                    for (int r = 0; r < 4; ++r) {
                        int rl = wr * 64 + m * 16 + g * 4 + r;
                        int cl = wc * 64 + n * 16 + fr;
                        int rr = row0 + rl;
                        int l = rr & 2047, nb_ = rr >> 11;
                        float own = acc[m][n][r];
                        float pr = bf2f((unsigned short)smem[rl * 128 + (cl ^ 64)]);
                        float c = posp[(size_t)l * HDIM + cl];
                        float s = posp[(size_t)SEQ * HDIM + (size_t)l * HDIM + cl];
                        float res = (cl < 64) ? (own * c - pr * s) : (own * c + pr * s);
                        size_t hb = (size_t)(nb_ * NHEAD + hB) * ((size_t)SEQ * HDIM);
                        dst[hb + (size_t)l * HDIM + cl] = f2bf(res);
                    }
        } else {
#pragma unroll
            for (int m = 0; m < 4; ++m)
#pragma unroll
                for (int n = 0; n < 4; ++n)
#pragma unroll
                    for (int r = 0; r < 4; ++r) {
                        int rr = row0 + wr * 64 + m * 16 + g * 4 + r;
                        int cl = wc * 64 + n * 16 + fr;   // hd
                        int l = rr & 2047, nb_ = rr >> 11;
                        size_t hb = (size_t)(nb_ * NHEAD + hB) * ((size_t)SEQ * HDIM);
                        vtb[hb + (size_t)cl * SEQ + l] = f2bf(acc[m][n][r]);  // V^T
                    }
        }
    }
#undef AT_
#undef BT_
}

// causal flash attention, swapped-QK^T, cooperative LDS-staged K/V.
// Q,K [nh][SEQ][HDIM], VT [nh][HDIM][SEQ] (all bf16), O [NB][SEQ][DM] bf16.
// 512 blocks; block l -> XCD l%8; XCD x owns heads 4x..4x+3 (K/V L2-resident).
// Block does q-tiles p and 15-p (128 rows, 4 waves x 32). All waves share a
// block-uniform kbi loop; K/V tiles double-buffered in LDS via
// global_load_lds w=16 with XOR-swizzled per-lane global sources (LDS linear).
__global__ __launch_bounds__(256, 2) void attn_k(const unsigned short* __restrict__ Q,
                                                 const unsigned short* __restrict__ K,
                                                 const unsigned short* __restrict__ VT,
                                                 unsigned short* __restrict__ O)
{
    const int lb = blockIdx.x;            // 0..511
    const int xcd = lb & 7, idx = lb >> 3;
    const int nh = xcd * 4 + (idx >> 4);  // heads grouped per XCD
    const int p = idx & 15;
    const int tid = threadIdx.x;
    const int w = tid >> 6, lane = tid & 63;
    const int g = lane >> 4, fr = lane & 15;
    const float scale = 0.08838834764831845f;  // 1/sqrt(128)

    const unsigned short* Qh = Q + (size_t)nh * SEQ * HDIM;
    const unsigned short* Kh = K + (size_t)nh * SEQ * HDIM;
    const unsigned short* Vh = VT + (size_t)nh * SEQ * HDIM;  // [128][SEQ]
    const int nb = nh >> 4, h = nh & 15;

    __shared__ unsigned short Kt[2][4096];  // [32 keys][128 d], 16B-slot XOR (row&7)
    __shared__ unsigned short Vt[2][4096];  // [128 d][32 keys], 16B-slot XOR (d&3)
    __shared__ unsigned Plds[4][2][320];    // per-wave P^T bounce, row stride 20 u32

    // stage K/V tile kbi into buffer bf (all 256 threads; LDS dest linear)
    auto stage = [&](int bf, int kbi) {
        const int key0 = kbi * 32;
#pragma unroll
        for (int c = 0; c < 2; ++c) {
            int r = c * 16 + (tid >> 4);              // K row (key)
            int sK = tid & 15;                        // 16B slot in 256B row
            gload16(Kh + (size_t)(key0 + r) * HDIM + 8 * (sK ^ (r & 7)),
                    &Kt[bf][c * 2048 + w * 512]);
            int d = c * 64 + (tid >> 2);              // V row (dim)
            int sV = tid & 3;                         // 16B slot in 64B row
            gload16(Vh + (size_t)d * SEQ + key0 + 8 * (sV ^ (d & 3)),
                    &Vt[bf][c * 2048 + w * 512]);
        }
    };

    for (int pass = 0; pass < 2; ++pass) {
        const int tile = pass ? (15 - p) : p;
        const int qt = tile * 128 + w * 32;
        const int nkb_w = 4 * tile + w;        // this wave's inclusive bound
        const int nkb_blk = 4 * tile + 3;      // block-uniform bound

        short8 qf[2][4];
#pragma unroll
        for (int u = 0; u < 2; ++u)
#pragma unroll
            for (int kk = 0; kk < 4; ++kk)
                qf[u][kk] = *(const short8*)(Qh + (size_t)(qt + u * 16 + fr) * HDIM + kk * 32 + g * 8);

        const f32x4 fz = {0.f, 0.f, 0.f, 0.f};
        f32x4 oacc[2][8];
#pragma unroll
        for (int u = 0; u < 2; ++u)
#pragma unroll
            for (int f = 0; f < 8; ++f) oacc[u][f] = fz;
        float mrow[2] = {-3e38f, -3e38f}, lrow[2] = {0.f, 0.f};

        stage(0, 0);
        int buf = 0;
        __syncthreads();   // vmcnt(0) drained at barrier -> tile 0 ready

        for (int kbi = 0; kbi <= nkb_blk; ++kbi) {
            if (kbi < nkb_blk) stage(buf ^ 1, kbi + 1);

            if (kbi <= nkb_w) {
                const int key0 = kbi * 32;
                short8 kf[2][4];
#pragma unroll
                for (int hh = 0; hh < 2; ++hh)
#pragma unroll
                    for (int kk = 0; kk < 4; ++kk)
                        kf[hh][kk] = *(const short8*)&Kt[buf][(hh * 16 + fr) * 128 + 8 * ((4 * kk + g) ^ (fr & 7))];

                f32x4 s[2][2];
#pragma unroll
                for (int u = 0; u < 2; ++u) { s[u][0] = fz; s[u][1] = fz; }
                __builtin_amdgcn_s_setprio(1);
#pragma unroll
                for (int u = 0; u < 2; ++u)
#pragma unroll
                    for (int hh = 0; hh < 2; ++hh)
#pragma unroll
                        for (int kk = 0; kk < 4; ++kk)
                            s[u][hh] = __builtin_amdgcn_mfma_f32_16x16x32_bf16(kf[hh][kk], qf[u][kk], s[u][hh], 0, 0, 0);
                __builtin_amdgcn_s_setprio(0);

#pragma unroll
                for (int u = 0; u < 2; ++u) {
                    const int q = qt + u * 16 + fr;
#pragma unroll
                    for (int hh = 0; hh < 2; ++hh)
#pragma unroll
                        for (int r = 0; r < 4; ++r) {
                            int key = key0 + hh * 16 + 4 * g + r;
                            float v = s[u][hh][r] * scale;
                            s[u][hh][r] = (key <= q) ? v : -1e30f;
                        }
                    float mx = fmaxf(fmaxf(fmaxf(s[u][0][0], s[u][0][1]), fmaxf(s[u][0][2], s[u][0][3])),
                                     fmaxf(fmaxf(s[u][1][0], s[u][1][1]), fmaxf(s[u][1][2], s[u][1][3])));
                    mx = fmaxf(mx, __shfl_xor(mx, 16, 64));
                    mx = fmaxf(mx, __shfl_xor(mx, 32, 64));
                    // defer-max (T13): only rescale when max grew past threshold
                    if (!__all(mx <= mrow[u] + 8.f)) {
                        float mn = fmaxf(mrow[u], mx);
                        float al = __expf(mrow[u] - mn);
                        mrow[u] = mn;
                        lrow[u] *= al;
#pragma unroll
                        for (int f = 0; f < 8; ++f)
#pragma unroll
                            for (int r = 0; r < 4; ++r) oacc[u][f][r] *= al;
                    }
                    float pv[2][4];
                    float ps = 0.f;
#pragma unroll
                    for (int hh = 0; hh < 2; ++hh)
#pragma unroll
                        for (int r = 0; r < 4; ++r) {
                            float e = __expf(s[u][hh][r] - mrow[u]);
                            pv[hh][r] = e;
                            ps += e;
                        }
                    ps += __shfl_xor(ps, 16, 64);
                    ps += __shfl_xor(ps, 32, 64);
                    lrow[u] += ps;
                    // P^T bounce: word kw holds keys {2kw,2kw+1}
                    unsigned* Pw = &Plds[w][u][0];
#pragma unroll
                    for (int hh = 0; hh < 2; ++hh) {
                        Pw[fr * 20 + hh * 8 + 2 * g + 0] = pk2bf(pv[hh][0], pv[hh][1]);
                        Pw[fr * 20 + hh * 8 + 2 * g + 1] = pk2bf(pv[hh][2], pv[hh][3]);
                    }
                }
                short8 vf[8];
#pragma unroll
                for (int f = 0; f < 8; ++f)
                    vf[f] = *(const short8*)&Vt[buf][(f * 16 + fr) * 32 + 8 * (g ^ (fr & 3))];
                asm volatile("s_waitcnt lgkmcnt(0)" ::: "memory");
                short8 pf[2];
#pragma unroll
                for (int u = 0; u < 2; ++u)
                    pf[u] = *(const short8*)&Plds[w][u][fr * 20 + g * 4];

                __builtin_amdgcn_s_setprio(1);
#pragma unroll
                for (int u = 0; u < 2; ++u)
#pragma unroll
                    for (int f = 0; f < 8; ++f)
                        oacc[u][f] = __builtin_amdgcn_mfma_f32_16x16x32_bf16(vf[f], pf[u], oacc[u][f], 0, 0, 0);
                __builtin_amdgcn_s_setprio(0);
            }
            __syncthreads();   // staging of buf^1 complete; all reads of buf done
            buf ^= 1;
        }

        // epilogue: O^T layout -> lane (g,fr): q = qt+16u+fr, d = f*16+4g+r
#pragma unroll
        for (int u = 0; u < 2; ++u) {
            const float inv = 1.0f / lrow[u];
            const size_t obase = ((size_t)nb * SEQ + qt + u * 16 + fr) * DM + h * HDIM;
#pragma unroll
            for (int f = 0; f < 8; ++f) {
                unsigned w0 = pk2bf(oacc[u][f][0] * inv, oacc[u][f][1] * inv);
                unsigned w1 = pk2bf(oacc[u][f][2] * inv, oacc[u][f][3] * inv);
                unsigned* dstp = (unsigned*)(O + obase + f * 16 + 4 * g);
                dstp[0] = w0;
                dstp[1] = w1;
            }
        }
    }
}

extern "C" void kernel_launch(void* const* d_in, const int* in_sizes, int n_in,
                              void* d_out, int out_size, void* d_ws, size_t ws_size,
                              hipStream_t stream) {
    const float* x    = (const float*)d_in[0];   // [2,2048,2048]
    const float* pos  = (const float*)d_in[1];   // [2,2048,128]
    const float* wqkv = (const float*)d_in[2];   // [6144,2048]
    const float* wo   = (const float*)d_in[3];   // [2048,2048]
    float* out = (float*)d_out;

    const size_t HBUF = (size_t)NB * NHEAD * SEQ * HDIM;  // 8Mi elems = 16MiB
    unsigned short* qb  = (unsigned short*)d_ws;
    unsigned short* kbuf = qb + HBUF;
    unsigned short* vtb = kbuf + HBUF;
    unsigned short* ob  = vtb + HBUF;

    // 1) QKV projection + RoPE(Q,K) + scatter into head layouts (V transposed)
    gemm_bt<0, 1><<<dim3(48, 32), 256, 0, stream>>>(x, wqkv, 2048, qb, kbuf, vtb, nullptr, pos);
    // 2) causal flash attention (swapped-QK, LDS-staged K/V, XCD head grouping)
    attn_k<<<dim3(512), 256, 0, stream>>>(qb, kbuf, vtb, ob);
    // 3) output projection -> f32 d_out
    gemm_bt<1, 0><<<dim3(16, 32), 256, 0, stream>>>(ob, wo, 2048, nullptr, nullptr, nullptr, out, nullptr);
}

// Round 5
// 355.920 us; speedup vs baseline: 2.2281x; 1.0928x over previous
//
#include <hip/hip_runtime.h>

typedef __attribute__((ext_vector_type(8))) short short8;
typedef __attribute__((ext_vector_type(4))) float f32x4;

#define NB 2
#define SEQ 2048
#define DM 2048
#define NHEAD 16
#define HDIM 128

__device__ __forceinline__ unsigned short f2bf(float f) {
    unsigned u = __float_as_uint(f);
    u += 0x7fffu + ((u >> 16) & 1u);   // round-to-nearest-even (finite vals)
    return (unsigned short)(u >> 16);
}
__device__ __forceinline__ float bf2f(unsigned short h) {
    return __uint_as_float(((unsigned)h) << 16);
}
__device__ __forceinline__ unsigned pk2bf(float a, float b) {
    return (unsigned)f2bf(a) | ((unsigned)f2bf(b) << 16);
}
// async global->LDS, 16B per lane. LDS dest must be wave-uniform base;
// HW writes base + lane*16. Global src is per-lane.
__device__ __forceinline__ void gload16(const unsigned short* g, unsigned short* l) {
    __builtin_amdgcn_global_load_lds((const __attribute__((address_space(1))) void*)g,
                                     (__attribute__((address_space(3))) void*)l,
                                     16, 0, 0);
}

// f32 -> bf16 stream converter, two segments (x, w_qkv). n*8 elements each.
__global__ __launch_bounds__(256) void cvt_bf16(const float* __restrict__ a,
                                                unsigned short* __restrict__ oa, int na8,
                                                const float* __restrict__ b,
                                                unsigned short* __restrict__ ob, int nb8)
{
    const int t0 = blockIdx.x * 256 + threadIdx.x;
    const int stride = gridDim.x * 256;
    for (int i = t0; i < na8; i += stride) {
        const f32x4* src = (const f32x4*)(a + (size_t)i * 8);
        f32x4 lo = src[0], hi = src[1];
        short8 v;
#pragma unroll
        for (int j = 0; j < 4; ++j) { v[j] = (short)f2bf(lo[j]); v[j + 4] = (short)f2bf(hi[j]); }
        *(short8*)(oa + (size_t)i * 8) = v;
    }
    for (int i = t0; i < nb8; i += stride) {
        const f32x4* src = (const f32x4*)(b + (size_t)i * 8);
        f32x4 lo = src[0], hi = src[1];
        short8 v;
#pragma unroll
        for (int j = 0; j < 4; ++j) { v[j] = (short)f2bf(lo[j]); v[j + 4] = (short)f2bf(hi[j]); }
        *(short8*)(ob + (size_t)i * 8) = v;
    }
}

// C = A * B^T, both bf16 [rows][K] row-major. 128x128 tile, BK=32, 256 thr
// (4 waves 2x2), global_load_lds w=16 staging, 1 barrier/K-step (m97 form).
// 1-D grid with bijective XCD swizzle (nwg%8==0). QKV scatter + fused RoPE
// epilogue (each 128-col block is exactly one (which,head) span).
__global__ __launch_bounds__(256) void gemm_qkv(const unsigned short* __restrict__ A,
                                                const unsigned short* __restrict__ B,
                                                int K, int NBX,
                                                unsigned short* __restrict__ qb,
                                                unsigned short* __restrict__ kb,
                                                unsigned short* __restrict__ vtb,
                                                const float* __restrict__ posp)
{
    __shared__ unsigned short smem[16384];  // At[2][4096] | Bt[2][4096]; epi reuse [128][128]
    const int tid = threadIdx.x;
    const int lane = tid & 63, w = tid >> 6;
    const int wr = w >> 1, wc = w & 1;
    const int g = lane >> 4, fr = lane & 15;
    const int lr = lane >> 2, ls = lane & 3;     // staging: row-in-16, 16B slot
    // XCD-aware bijective remap: XCD x owns 4 contiguous M-rows of blocks
    const int nwg = gridDim.x, qx = nwg >> 3;
    const int swz = ((int)blockIdx.x & 7) * qx + ((int)blockIdx.x >> 3);
    const int bx = swz % NBX, by = swz / NBX;
    const int row0 = by * 128, col0 = bx * 128;

    auto stage = [&](int b, int kt) {
        const int k0 = kt * 32;
#pragma unroll
        for (int c = 0; c < 2; ++c) {
            const int r = c * 64 + w * 16;       // wave-uniform row base in tile
            gload16(A + (size_t)(row0 + r + lr) * K + k0 + ls * 8,
                    smem + b * 4096 + r * 32);
            gload16(B + (size_t)(col0 + r + lr) * K + k0 + ls * 8,
                    smem + 8192 + b * 4096 + r * 32);
        }
    };

    const f32x4 fz = {0.f, 0.f, 0.f, 0.f};
    f32x4 acc[4][4];
#pragma unroll
    for (int m = 0; m < 4; ++m)
#pragma unroll
        for (int n = 0; n < 4; ++n) acc[m][n] = fz;

    const int nk = K / 32;
    stage(0, 0);
    __syncthreads();   // vmcnt(0) drained -> tile 0 ready
    for (int kt = 0; kt < nk; ++kt) {
        const int cur = kt & 1;
        if (kt + 1 < nk) stage(cur ^ 1, kt + 1);
        short8 af[4], bfv[4];
#pragma unroll
        for (int m = 0; m < 4; ++m)
            af[m] = *(const short8*)&smem[cur * 4096 + (wr * 64 + m * 16 + fr) * 32 + g * 8];
#pragma unroll
        for (int n = 0; n < 4; ++n)
            bfv[n] = *(const short8*)&smem[8192 + cur * 4096 + (wc * 64 + n * 16 + fr) * 32 + g * 8];
#pragma unroll
        for (int m = 0; m < 4; ++m)
#pragma unroll
            for (int n = 0; n < 4; ++n)
                acc[m][n] = __builtin_amdgcn_mfma_f32_16x16x32_bf16(
                    af[m], bfv[n], acc[m][n], 0, 0, 0);
        __syncthreads();   // reads of cur done; staging of cur^1 landed
    }

    // ---- QKV scatter epilogue with fused RoPE (Q/K) ----
    const int which = col0 >> 11;        // 0=Q 1=K 2=V (uniform per block)
    const int hB = (col0 >> 7) & 15;     // head (uniform per block)
    if (which < 2) {
        // stash whole C-tile as bf16 into smem[128][128] for pair exchange
#pragma unroll
        for (int m = 0; m < 4; ++m)
#pragma unroll
            for (int n = 0; n < 4; ++n)
#pragma unroll
                for (int r = 0; r < 4; ++r) {
                    int rl = wr * 64 + m * 16 + g * 4 + r;
                    int cl = wc * 64 + n * 16 + fr;
                    smem[rl * 128 + cl] = f2bf(acc[m][n][r]);
                }
        __syncthreads();
        unsigned short* dst = which ? kb : qb;
#pragma unroll
        for (int m = 0; m < 4; ++m)
#pragma unroll
            for (int n = 0; n < 4; ++n)
#pragma unroll
                for (int r = 0; r < 4; ++r) {
                    int rl = wr * 64 + m * 16 + g * 4 + r;
                    int cl = wc * 64 + n * 16 + fr;
                    int rr = row0 + rl;
                    int l = rr & 2047, nb_ = rr >> 11;
                    float own = acc[m][n][r];
                    float pr = bf2f(smem[rl * 128 + (cl ^ 64)]);
                    float c = posp[(size_t)l * HDIM + cl];
                    float s = posp[(size_t)SEQ * HDIM + (size_t)l * HDIM + cl];
                    float res = (cl < 64) ? (own * c - pr * s) : (own * c + pr * s);
                    size_t hb = (size_t)(nb_ * NHEAD + hB) * ((size_t)SEQ * HDIM);
                    dst[hb + (size_t)l * HDIM + cl] = f2bf(res);
                }
    } else {
#pragma unroll
        for (int m = 0; m < 4; ++m)
#pragma unroll
            for (int n = 0; n < 4; ++n)
#pragma unroll
                for (int r = 0; r < 4; ++r) {
                    int rr = row0 + wr * 64 + m * 16 + g * 4 + r;
                    int cl = wc * 64 + n * 16 + fr;   // hd
                    int l = rr & 2047, nb_ = rr >> 11;
                    size_t hb = (size_t)(nb_ * NHEAD + hB) * ((size_t)SEQ * HDIM);
                    vtb[hb + (size_t)cl * SEQ + l] = f2bf(acc[m][n][r]);  // V^T
                }
    }
}

// out-proj GEMM: A bf16 [M][K], B f32 [N][K] reg-staged+converted. 128x128,
// BK=32, f32 store. (round-4 structure, unchanged)
__global__ __launch_bounds__(256) void gemm_out(const unsigned short* __restrict__ Aup,
                                                const float* __restrict__ Bf,
                                                int K, float* __restrict__ outf)
{
    __shared__ short At[2][128 * 32];
    __shared__ short Bt[2][128 * 32];
    const int tid = threadIdx.x;
    const int lane = tid & 63;
    const int w = tid >> 6;
    const int wr = w >> 1, wc = w & 1;
    const int g = lane >> 4, fr = lane & 15;
    const int row0 = blockIdx.y * 128, col0 = blockIdx.x * 128;
    const int sr = tid >> 2;
    const int sc = (tid & 3) * 8;

    const f32x4 fz = {0.f, 0.f, 0.f, 0.f};
    f32x4 acc[4][4];
#pragma unroll
    for (int m = 0; m < 4; ++m)
#pragma unroll
        for (int n = 0; n < 4; ++n) acc[m][n] = fz;

    f32x4 brf[2][2];
    short8 aru[2];

    auto load_regs = [&](int kt) {
        int k0 = kt * 32;
#pragma unroll
        for (int i = 0; i < 2; ++i) {
            size_t ga = (size_t)(row0 + sr + i * 64) * K + k0 + sc;
            size_t gb = (size_t)(col0 + sr + i * 64) * K + k0 + sc;
            aru[i] = *(const short8*)(Aup + ga);
            brf[i][0] = *(const f32x4*)(Bf + gb);
            brf[i][1] = *(const f32x4*)(Bf + gb + 4);
        }
    };
    auto write_lds = [&](int b) {
#pragma unroll
        for (int i = 0; i < 2; ++i) {
            *(short8*)&At[b][(sr + i * 64) * 32 + sc] = aru[i];
            short8 bv;
#pragma unroll
            for (int j = 0; j < 8; ++j) bv[j] = (short)f2bf(brf[i][j >> 2][j & 3]);
            *(short8*)&Bt[b][(sr + i * 64) * 32 + sc] = bv;
        }
    };

    const int nk = K / 32;
    load_regs(0);
    write_lds(0);
    __syncthreads();
    for (int kt = 0; kt < nk; ++kt) {
        const int cur = kt & 1;
        if (kt + 1 < nk) load_regs(kt + 1);
        short8 af[4], bfv[4];
#pragma unroll
        for (int m = 0; m < 4; ++m)
            af[m] = *(const short8*)&At[cur][(wr * 64 + m * 16 + fr) * 32 + g * 8];
#pragma unroll
        for (int n = 0; n < 4; ++n)
            bfv[n] = *(const short8*)&Bt[cur][(wc * 64 + n * 16 + fr) * 32 + g * 8];
#pragma unroll
        for (int m = 0; m < 4; ++m)
#pragma unroll
            for (int n = 0; n < 4; ++n)
                acc[m][n] = __builtin_amdgcn_mfma_f32_16x16x32_bf16(
                    af[m], bfv[n], acc[m][n], 0, 0, 0);
        __syncthreads();
        if (kt + 1 < nk) write_lds((kt + 1) & 1);
        __syncthreads();
    }

#pragma unroll
    for (int m = 0; m < 4; ++m)
#pragma unroll
        for (int n = 0; n < 4; ++n)
#pragma unroll
            for (int r = 0; r < 4; ++r) {
                int rr = row0 + wr * 64 + m * 16 + g * 4 + r;
                int cc = col0 + wc * 64 + n * 16 + fr;
                outf[(size_t)rr * 2048 + cc] = acc[m][n][r];
            }
}

// causal flash attention, swapped-QK^T, cooperative LDS-staged K/V.
// (round-4 kernel, unchanged)
__global__ __launch_bounds__(256, 2) void attn_k(const unsigned short* __restrict__ Q,
                                                 const unsigned short* __restrict__ K,
                                                 const unsigned short* __restrict__ VT,
                                                 unsigned short* __restrict__ O)
{
    const int lb = blockIdx.x;            // 0..511
    const int xcd = lb & 7, idx = lb >> 3;
    const int nh = xcd * 4 + (idx >> 4);  // heads grouped per XCD
    const int p = idx & 15;
    const int tid = threadIdx.x;
    const int w = tid >> 6, lane = tid & 63;
    const int g = lane >> 4, fr = lane & 15;
    const float scale = 0.08838834764831845f;  // 1/sqrt(128)

    const unsigned short* Qh = Q + (size_t)nh * SEQ * HDIM;
    const unsigned short* Kh = K + (size_t)nh * SEQ * HDIM;
    const unsigned short* Vh = VT + (size_t)nh * SEQ * HDIM;  // [128][SEQ]
    const int nb = nh >> 4, h = nh & 15;

    __shared__ unsigned short Kt[2][4096];  // [32 keys][128 d], 16B-slot XOR (row&7)
    __shared__ unsigned short Vt[2][4096];  // [128 d][32 keys], 16B-slot XOR (d&3)
    __shared__ unsigned Plds[4][2][320];    // per-wave P^T bounce, row stride 20 u32

    auto stage = [&](int bf, int kbi) {
        const int key0 = kbi * 32;
#pragma unroll
        for (int c = 0; c < 2; ++c) {
            int r = c * 16 + (tid >> 4);              // K row (key)
            int sK = tid & 15;                        // 16B slot in 256B row
            gload16(Kh + (size_t)(key0 + r) * HDIM + 8 * (sK ^ (r & 7)),
                    &Kt[bf][c * 2048 + w * 512]);
            int d = c * 64 + (tid >> 2);              // V row (dim)
            int sV = tid & 3;                         // 16B slot in 64B row
            gload16(Vh + (size_t)d * SEQ + key0 + 8 * (sV ^ (d & 3)),
                    &Vt[bf][c * 2048 + w * 512]);
        }
    };

    for (int pass = 0; pass < 2; ++pass) {
        const int tile = pass ? (15 - p) : p;
        const int qt = tile * 128 + w * 32;
        const int nkb_w = 4 * tile + w;        // this wave's inclusive bound
        const int nkb_blk = 4 * tile + 3;      // block-uniform bound

        short8 qf[2][4];
#pragma unroll
        for (int u = 0; u < 2; ++u)
#pragma unroll
            for (int kk = 0; kk < 4; ++kk)
                qf[u][kk] = *(const short8*)(Qh + (size_t)(qt + u * 16 + fr) * HDIM + kk * 32 + g * 8);

        const f32x4 fz = {0.f, 0.f, 0.f, 0.f};
        f32x4 oacc[2][8];
#pragma unroll
        for (int u = 0; u < 2; ++u)
#pragma unroll
            for (int f = 0; f < 8; ++f) oacc[u][f] = fz;
        float mrow[2] = {-3e38f, -3e38f}, lrow[2] = {0.f, 0.f};

        stage(0, 0);
        int buf = 0;
        __syncthreads();

        for (int kbi = 0; kbi <= nkb_blk; ++kbi) {
            if (kbi < nkb_blk) stage(buf ^ 1, kbi + 1);

            if (kbi <= nkb_w) {
                const int key0 = kbi * 32;
                short8 kf[2][4];
#pragma unroll
                for (int hh = 0; hh < 2; ++hh)
#pragma unroll
                    for (int kk = 0; kk < 4; ++kk)
                        kf[hh][kk] = *(const short8*)&Kt[buf][(hh * 16 + fr) * 128 + 8 * ((4 * kk + g) ^ (fr & 7))];

                f32x4 s[2][2];
#pragma unroll
                for (int u = 0; u < 2; ++u) { s[u][0] = fz; s[u][1] = fz; }
                __builtin_amdgcn_s_setprio(1);
#pragma unroll
                for (int u = 0; u < 2; ++u)
#pragma unroll
                    for (int hh = 0; hh < 2; ++hh)
#pragma unroll
                        for (int kk = 0; kk < 4; ++kk)
                            s[u][hh] = __builtin_amdgcn_mfma_f32_16x16x32_bf16(kf[hh][kk], qf[u][kk], s[u][hh], 0, 0, 0);
                __builtin_amdgcn_s_setprio(0);

#pragma unroll
                for (int u = 0; u < 2; ++u) {
                    const int q = qt + u * 16 + fr;
#pragma unroll
                    for (int hh = 0; hh < 2; ++hh)
#pragma unroll
                        for (int r = 0; r < 4; ++r) {
                            int key = key0 + hh * 16 + 4 * g + r;
                            float v = s[u][hh][r] * scale;
                            s[u][hh][r] = (key <= q) ? v : -1e30f;
                        }
                    float mx = fmaxf(fmaxf(fmaxf(s[u][0][0], s[u][0][1]), fmaxf(s[u][0][2], s[u][0][3])),
                                     fmaxf(fmaxf(s[u][1][0], s[u][1][1]), fmaxf(s[u][1][2], s[u][1][3])));
                    mx = fmaxf(mx, __shfl_xor(mx, 16, 64));
                    mx = fmaxf(mx, __shfl_xor(mx, 32, 64));
                    if (!__all(mx <= mrow[u] + 8.f)) {
                        float mn = fmaxf(mrow[u], mx);
                        float al = __expf(mrow[u] - mn);
                        mrow[u] = mn;
                        lrow[u] *= al;
#pragma unroll
                        for (int f = 0; f < 8; ++f)
#pragma unroll
                            for (int r = 0; r < 4; ++r) oacc[u][f][r] *= al;
                    }
                    float pv[2][4];
                    float ps = 0.f;
#pragma unroll
                    for (int hh = 0; hh < 2; ++hh)
#pragma unroll
                        for (int r = 0; r < 4; ++r) {
                            float e = __expf(s[u][hh][r] - mrow[u]);
                            pv[hh][r] = e;
                            ps += e;
                        }
                    ps += __shfl_xor(ps, 16, 64);
                    ps += __shfl_xor(ps, 32, 64);
                    lrow[u] += ps;
                    unsigned* Pw = &Plds[w][u][0];
#pragma unroll
                    for (int hh = 0; hh < 2; ++hh) {
                        Pw[fr * 20 + hh * 8 + 2 * g + 0] = pk2bf(pv[hh][0], pv[hh][1]);
                        Pw[fr * 20 + hh * 8 + 2 * g + 1] = pk2bf(pv[hh][2], pv[hh][3]);
                    }
                }
                short8 vf[8];
#pragma unroll
                for (int f = 0; f < 8; ++f)
                    vf[f] = *(const short8*)&Vt[buf][(f * 16 + fr) * 32 + 8 * (g ^ (fr & 3))];
                asm volatile("s_waitcnt lgkmcnt(0)" ::: "memory");
                short8 pf[2];
#pragma unroll
                for (int u = 0; u < 2; ++u)
                    pf[u] = *(const short8*)&Plds[w][u][fr * 20 + g * 4];

                __builtin_amdgcn_s_setprio(1);
#pragma unroll
                for (int u = 0; u < 2; ++u)
#pragma unroll
                    for (int f = 0; f < 8; ++f)
                        oacc[u][f] = __builtin_amdgcn_mfma_f32_16x16x32_bf16(vf[f], pf[u], oacc[u][f], 0, 0, 0);
                __builtin_amdgcn_s_setprio(0);
            }
            __syncthreads();
            buf ^= 1;
        }

#pragma unroll
        for (int u = 0; u < 2; ++u) {
            const float inv = 1.0f / lrow[u];
            const size_t obase = ((size_t)nb * SEQ + qt + u * 16 + fr) * DM + h * HDIM;
#pragma unroll
            for (int f = 0; f < 8; ++f) {
                unsigned w0 = pk2bf(oacc[u][f][0] * inv, oacc[u][f][1] * inv);
                unsigned w1 = pk2bf(oacc[u][f][2] * inv, oacc[u][f][3] * inv);
                unsigned* dstp = (unsigned*)(O + obase + f * 16 + 4 * g);
                dstp[0] = w0;
                dstp[1] = w1;
            }
        }
    }
}

extern "C" void kernel_launch(void* const* d_in, const int* in_sizes, int n_in,
                              void* d_out, int out_size, void* d_ws, size_t ws_size,
                              hipStream_t stream) {
    const float* x    = (const float*)d_in[0];   // [2,2048,2048]
    const float* pos  = (const float*)d_in[1];   // [2,2048,128]
    const float* wqkv = (const float*)d_in[2];   // [6144,2048]
    const float* wo   = (const float*)d_in[3];   // [2048,2048]
    float* out = (float*)d_out;

    const size_t HBUF = (size_t)NB * NHEAD * SEQ * HDIM;  // 8Mi elems = 16MiB
    unsigned short* qb   = (unsigned short*)d_ws;
    unsigned short* kbuf = qb + HBUF;
    unsigned short* vtb  = kbuf + HBUF;
    unsigned short* obx  = vtb + HBUF;        // x_bf16 during gemm1, then attn O
    unsigned short* wqkvbf = (unsigned short*)d_out;  // 24MiB scratch in d_out
                                              // (dead before gemm_out rewrites d_out)

    // 0) pre-convert x and w_qkv to bf16 (x into obx, w_qkv into d_out scratch)
    cvt_bf16<<<dim3(2048), 256, 0, stream>>>(x, obx, 1048576, wqkv, wqkvbf, 1572864);
    // 1) QKV projection (bf16 x bf16, gload_lds staging) + RoPE + head scatter
    gemm_qkv<<<dim3(1536), 256, 0, stream>>>(obx, wqkvbf, 2048, 48, qb, kbuf, vtb, pos);
    // 2) causal flash attention (overwrites obx with attention output)
    attn_k<<<dim3(512), 256, 0, stream>>>(qb, kbuf, vtb, obx);
    // 3) output projection -> f32 d_out
    gemm_out<<<dim3(16, 32), 256, 0, stream>>>(obx, wo, 2048, out);
}

// Round 6
// 325.747 us; speedup vs baseline: 2.4345x; 1.0926x over previous
//
#include <hip/hip_runtime.h>

typedef __attribute__((ext_vector_type(8))) short short8;
typedef __attribute__((ext_vector_type(4))) float f32x4;

#define NB 2
#define SEQ 2048
#define DM 2048
#define NHEAD 16
#define HDIM 128

__device__ __forceinline__ unsigned short f2bf(float f) {
    unsigned u = __float_as_uint(f);
    u += 0x7fffu + ((u >> 16) & 1u);   // round-to-nearest-even (finite vals)
    return (unsigned short)(u >> 16);
}
__device__ __forceinline__ float bf2f(unsigned short h) {
    return __uint_as_float(((unsigned)h) << 16);
}
__device__ __forceinline__ unsigned pk2bf(float a, float b) {
    return (unsigned)f2bf(a) | ((unsigned)f2bf(b) << 16);
}
// async global->LDS, 16B per lane. LDS dest must be wave-uniform base;
// HW writes base + lane*16. Global src is per-lane.
__device__ __forceinline__ void gload16(const unsigned short* g, unsigned short* l) {
    __builtin_amdgcn_global_load_lds((const __attribute__((address_space(1))) void*)g,
                                     (__attribute__((address_space(3))) void*)l,
                                     16, 0, 0);
}

// f32 -> bf16 stream converter, two segments. n*8 elements each.
__global__ __launch_bounds__(256) void cvt_bf16(const float* __restrict__ a,
                                                unsigned short* __restrict__ oa, int na8,
                                                const float* __restrict__ b,
                                                unsigned short* __restrict__ ob, int nb8)
{
    const int t0 = blockIdx.x * 256 + threadIdx.x;
    const int stride = gridDim.x * 256;
    for (int i = t0; i < na8; i += stride) {
        const f32x4* src = (const f32x4*)(a + (size_t)i * 8);
        f32x4 lo = src[0], hi = src[1];
        short8 v;
#pragma unroll
        for (int j = 0; j < 4; ++j) { v[j] = (short)f2bf(lo[j]); v[j + 4] = (short)f2bf(hi[j]); }
        *(short8*)(oa + (size_t)i * 8) = v;
    }
    for (int i = t0; i < nb8; i += stride) {
        const f32x4* src = (const f32x4*)(b + (size_t)i * 8);
        f32x4 lo = src[0], hi = src[1];
        short8 v;
#pragma unroll
        for (int j = 0; j < 4; ++j) { v[j] = (short)f2bf(lo[j]); v[j + 4] = (short)f2bf(hi[j]); }
        *(short8*)(ob + (size_t)i * 8) = v;
    }
}

// C = A * B^T, both bf16 [rows][K] row-major. 128x128 tile, BK=32, 256 thr
// (4 waves 2x2), global_load_lds w=16 staging, 1 barrier/K-step (m97 form).
// 1-D grid; block->XCD = bid%8. Per XCD: CPX cols; iterate 2-row x CPX-col
// super-chunks (A 1MB + B CPX/2 MB co-resident in the 4MB L2).
// EPI==0: f32 store. EPI==1: QKV scatter+layouts with fused RoPE.
template<int EPI, int CPX>
__global__ __launch_bounds__(256) void gemm_m97(const unsigned short* __restrict__ A,
                                                const unsigned short* __restrict__ B,
                                                int K,
                                                unsigned short* __restrict__ qb,
                                                unsigned short* __restrict__ kb,
                                                unsigned short* __restrict__ vtb,
                                                const float* __restrict__ posp,
                                                float* __restrict__ outf)
{
    __shared__ unsigned short smem[16384];  // At[2][4096] | Bt[2][4096]; epi reuse [128][128]
    const int tid = threadIdx.x;
    const int lane = tid & 63, w = tid >> 6;
    const int wr = w >> 1, wc = w & 1;
    const int g = lane >> 4, fr = lane & 15;
    const int lr = lane >> 2, ls = lane & 3;     // staging: row-in-16, 16B slot
    // XCD-aware chunked mapping
    const int x = blockIdx.x & 7, t = blockIdx.x >> 3;
    const int rp = t / (2 * CPX), wi = t % (2 * CPX);
    const int bx = x * CPX + (wi % CPX), by = rp * 2 + wi / CPX;
    const int row0 = by * 128, col0 = bx * 128;

    auto stage = [&](int b, int kt) {
        const int k0 = kt * 32;
#pragma unroll
        for (int c = 0; c < 2; ++c) {
            const int r = c * 64 + w * 16;       // wave-uniform row base in tile
            gload16(A + (size_t)(row0 + r + lr) * K + k0 + ls * 8,
                    smem + b * 4096 + r * 32);
            gload16(B + (size_t)(col0 + r + lr) * K + k0 + ls * 8,
                    smem + 8192 + b * 4096 + r * 32);
        }
    };

    const f32x4 fz = {0.f, 0.f, 0.f, 0.f};
    f32x4 acc[4][4];
#pragma unroll
    for (int m = 0; m < 4; ++m)
#pragma unroll
        for (int n = 0; n < 4; ++n) acc[m][n] = fz;

    const int nk = K / 32;
    stage(0, 0);
    __syncthreads();   // vmcnt(0) drained -> tile 0 ready
    for (int kt = 0; kt < nk; ++kt) {
        const int cur = kt & 1;
        if (kt + 1 < nk) stage(cur ^ 1, kt + 1);
        short8 af[4], bfv[4];
#pragma unroll
        for (int m = 0; m < 4; ++m)
            af[m] = *(const short8*)&smem[cur * 4096 + (wr * 64 + m * 16 + fr) * 32 + g * 8];
#pragma unroll
        for (int n = 0; n < 4; ++n)
            bfv[n] = *(const short8*)&smem[8192 + cur * 4096 + (wc * 64 + n * 16 + fr) * 32 + g * 8];
#pragma unroll
        for (int m = 0; m < 4; ++m)
#pragma unroll
            for (int n = 0; n < 4; ++n)
                acc[m][n] = __builtin_amdgcn_mfma_f32_16x16x32_bf16(
                    af[m], bfv[n], acc[m][n], 0, 0, 0);
        __syncthreads();   // reads of cur done; staging of cur^1 landed
    }

    if constexpr (EPI == 0) {
#pragma unroll
        for (int m = 0; m < 4; ++m)
#pragma unroll
            for (int n = 0; n < 4; ++n)
#pragma unroll
                for (int r = 0; r < 4; ++r) {
                    int rr = row0 + wr * 64 + m * 16 + g * 4 + r;
                    int cc = col0 + wc * 64 + n * 16 + fr;
                    outf[(size_t)rr * 2048 + cc] = acc[m][n][r];
                }
    } else {
        const int which = col0 >> 11;        // 0=Q 1=K 2=V (uniform per block)
        const int hB = (col0 >> 7) & 15;     // head (uniform per block)
        if (which < 2) {
            // stash whole C-tile as bf16 into smem[128][128] for pair exchange
#pragma unroll
            for (int m = 0; m < 4; ++m)
#pragma unroll
                for (int n = 0; n < 4; ++n)
#pragma unroll
                    for (int r = 0; r < 4; ++r) {
                        int rl = wr * 64 + m * 16 + g * 4 + r;
                        int cl = wc * 64 + n * 16 + fr;
                        smem[rl * 128 + cl] = f2bf(acc[m][n][r]);
                    }
            __syncthreads();
            unsigned short* dst = which ? kb : qb;
#pragma unroll
            for (int m = 0; m < 4; ++m)
#pragma unroll
                for (int n = 0; n < 4; ++n)
#pragma unroll
                    for (int r = 0; r < 4; ++r) {
                        int rl = wr * 64 + m * 16 + g * 4 + r;
                        int cl = wc * 64 + n * 16 + fr;
                        int rr = row0 + rl;
                        int l = rr & 2047, nb_ = rr >> 11;
                        float own = acc[m][n][r];
                        float pr = bf2f(smem[rl * 128 + (cl ^ 64)]);
                        float c = posp[(size_t)l * HDIM + cl];
                        float s = posp[(size_t)SEQ * HDIM + (size_t)l * HDIM + cl];
                        float res = (cl < 64) ? (own * c - pr * s) : (own * c + pr * s);
                        size_t hb = (size_t)(nb_ * NHEAD + hB) * ((size_t)SEQ * HDIM);
                        dst[hb + (size_t)l * HDIM + cl] = f2bf(res);
                    }
        } else {
#pragma unroll
            for (int m = 0; m < 4; ++m)
#pragma unroll
                for (int n = 0; n < 4; ++n)
#pragma unroll
                    for (int r = 0; r < 4; ++r) {
                        int rr = row0 + wr * 64 + m * 16 + g * 4 + r;
                        int cl = wc * 64 + n * 16 + fr;   // hd
                        int l = rr & 2047, nb_ = rr >> 11;
                        size_t hb = (size_t)(nb_ * NHEAD + hB) * ((size_t)SEQ * HDIM);
                        vtb[hb + (size_t)cl * SEQ + l] = f2bf(acc[m][n][r]);  // V^T
                    }
        }
    }
}

// causal flash attention, swapped-QK^T, cooperative LDS-staged K/V, KVBLK=64.
// Q,K [nh][SEQ][HDIM], VT [nh][HDIM][SEQ] (all bf16), O [NB][SEQ][DM] bf16.
// 512 blocks; block->XCD = bid%8; XCD x owns heads 4x..4x+3 (K/V L2-resident).
// Block does q-tiles p and 15-p (128 rows, 4 waves x 32). Per iteration one
// 64-key tile staged via global_load_lds w=16 (double-buffered, XOR-swizzled
// sources, linear LDS dest). P^T bounce is per-u sequential (one buffer).
__global__ __launch_bounds__(256, 2) void attn_k(const unsigned short* __restrict__ Q,
                                                 const unsigned short* __restrict__ K,
                                                 const unsigned short* __restrict__ VT,
                                                 unsigned short* __restrict__ O)
{
    const int lb = blockIdx.x;            // 0..511
    const int xcd = lb & 7, idx = lb >> 3;
    const int nh = xcd * 4 + (idx >> 4);  // heads grouped per XCD
    const int p = idx & 15;
    const int tid = threadIdx.x;
    const int w = tid >> 6, lane = tid & 63;
    const int g = lane >> 4, fr = lane & 15;
    const float scale = 0.08838834764831845f;  // 1/sqrt(128)

    const unsigned short* Qh = Q + (size_t)nh * SEQ * HDIM;
    const unsigned short* Kh = K + (size_t)nh * SEQ * HDIM;
    const unsigned short* Vh = VT + (size_t)nh * SEQ * HDIM;  // [128][SEQ]
    const int nb = nh >> 4, h = nh & 15;

    __shared__ unsigned short Kt[2][8192];  // [64 keys][128 d], 16B-slot XOR (row&7)
    __shared__ unsigned short Vt[2][8192];  // [128 d][64 keys], 16B-slot XOR (d&7)
    __shared__ unsigned Plds[4][576];       // per-wave P^T, 16 rows x 36 words (144B)

    auto stage = [&](int bf, int kbi) {
        const int key0 = kbi * 64;
#pragma unroll
        for (int c = 0; c < 4; ++c) {
            int r = c * 16 + (tid >> 4);              // K row (key 0..63)
            int sK = tid & 15;                        // 16B slot in 256B row
            gload16(Kh + (size_t)(key0 + r) * HDIM + 8 * (sK ^ (r & 7)),
                    &Kt[bf][c * 2048 + w * 512]);
            int d = c * 32 + (tid >> 3);              // V row (dim 0..127)
            int sV = tid & 7;                         // 16B slot in 128B row
            gload16(Vh + (size_t)d * SEQ + key0 + 8 * (sV ^ (d & 7)),
                    &Vt[bf][c * 2048 + w * 512]);
        }
    };

    for (int pass = 0; pass < 2; ++pass) {
        const int tile = pass ? (15 - p) : p;
        const int qt = tile * 128 + w * 32;
        const int nkb_w = (qt + 31) >> 6;      // wave's inclusive 64-key bound
        const int nkb_blk = 2 * tile + 1;      // block-uniform bound

        short8 qf[2][4];
#pragma unroll
        for (int u = 0; u < 2; ++u)
#pragma unroll
            for (int kk = 0; kk < 4; ++kk)
                qf[u][kk] = *(const short8*)(Qh + (size_t)(qt + u * 16 + fr) * HDIM + kk * 32 + g * 8);

        const f32x4 fz = {0.f, 0.f, 0.f, 0.f};
        f32x4 oacc[2][8];
#pragma unroll
        for (int u = 0; u < 2; ++u)
#pragma unroll
            for (int f = 0; f < 8; ++f) oacc[u][f] = fz;
        float mrow[2] = {-3e38f, -3e38f}, lrow[2] = {0.f, 0.f};

        stage(0, 0);
        int buf = 0;
        __syncthreads();   // vmcnt(0) drained -> tile 0 ready

        for (int kbi = 0; kbi <= nkb_blk; ++kbi) {
            if (kbi < nkb_blk) stage(buf ^ 1, kbi + 1);

            if (kbi <= nkb_w) {
                const int key0 = kbi * 64;
                f32x4 s[2][4];
#pragma unroll
                for (int u = 0; u < 2; ++u)
#pragma unroll
                    for (int hh = 0; hh < 4; ++hh) s[u][hh] = fz;

                __builtin_amdgcn_s_setprio(1);
#pragma unroll
                for (int hh = 0; hh < 4; ++hh) {
                    short8 kfh[4];
#pragma unroll
                    for (int kk = 0; kk < 4; ++kk)
                        kfh[kk] = *(const short8*)&Kt[buf][(hh * 16 + fr) * 128 + 8 * ((4 * kk + g) ^ (fr & 7))];
#pragma unroll
                    for (int u = 0; u < 2; ++u)
#pragma unroll
                        for (int kk = 0; kk < 4; ++kk)
                            s[u][hh] = __builtin_amdgcn_mfma_f32_16x16x32_bf16(kfh[kk], qf[u][kk], s[u][hh], 0, 0, 0);
                }
                __builtin_amdgcn_s_setprio(0);

#pragma unroll
                for (int u = 0; u < 2; ++u) {
                    const int q = qt + u * 16 + fr;
#pragma unroll
                    for (int hh = 0; hh < 4; ++hh)
#pragma unroll
                        for (int r = 0; r < 4; ++r) {
                            int key = key0 + hh * 16 + 4 * g + r;
                            float v = s[u][hh][r] * scale;
                            s[u][hh][r] = (key <= q) ? v : -1e30f;
                        }
                    float mx = -3e38f;
#pragma unroll
                    for (int hh = 0; hh < 4; ++hh)
                        mx = fmaxf(mx, fmaxf(fmaxf(s[u][hh][0], s[u][hh][1]),
                                             fmaxf(s[u][hh][2], s[u][hh][3])));
                    mx = fmaxf(mx, __shfl_xor(mx, 16, 64));
                    mx = fmaxf(mx, __shfl_xor(mx, 32, 64));
                    // defer-max (T13): only rescale when max grew past threshold
                    if (!__all(mx <= mrow[u] + 8.f)) {
                        float mn = fmaxf(mrow[u], mx);
                        float al = __expf(mrow[u] - mn);
                        mrow[u] = mn;
                        lrow[u] *= al;
#pragma unroll
                        for (int f = 0; f < 8; ++f)
#pragma unroll
                            for (int r = 0; r < 4; ++r) oacc[u][f][r] *= al;
                    }
                    float pv[4][4];
                    float ps = 0.f;
#pragma unroll
                    for (int hh = 0; hh < 4; ++hh)
#pragma unroll
                        for (int r = 0; r < 4; ++r) {
                            float e = __expf(s[u][hh][r] - mrow[u]);
                            pv[hh][r] = e;
                            ps += e;
                        }
                    ps += __shfl_xor(ps, 16, 64);
                    ps += __shfl_xor(ps, 32, 64);
                    lrow[u] += ps;
                    // P^T bounce: word kw holds keys {2kw,2kw+1}; row q=fr
                    unsigned* Pw = &Plds[w][0];
#pragma unroll
                    for (int hh = 0; hh < 4; ++hh) {
                        Pw[fr * 36 + hh * 8 + 2 * g + 0] = pk2bf(pv[hh][0], pv[hh][1]);
                        Pw[fr * 36 + hh * 8 + 2 * g + 1] = pk2bf(pv[hh][2], pv[hh][3]);
                    }
                    asm volatile("s_waitcnt lgkmcnt(0)" ::: "memory");
                    short8 pf0 = *(const short8*)&Pw[fr * 36 + g * 4];
                    short8 pf1 = *(const short8*)&Pw[fr * 36 + 16 + g * 4];

                    __builtin_amdgcn_s_setprio(1);
#pragma unroll
                    for (int f = 0; f < 8; ++f) {
                        short8 vfa = *(const short8*)&Vt[buf][(f * 16 + fr) * 64 + 8 * (g ^ (fr & 7))];
                        short8 vfb = *(const short8*)&Vt[buf][(f * 16 + fr) * 64 + 8 * ((4 + g) ^ (fr & 7))];
                        oacc[u][f] = __builtin_amdgcn_mfma_f32_16x16x32_bf16(vfa, pf0, oacc[u][f], 0, 0, 0);
                        oacc[u][f] = __builtin_amdgcn_mfma_f32_16x16x32_bf16(vfb, pf1, oacc[u][f], 0, 0, 0);
                    }
                    __builtin_amdgcn_s_setprio(0);
                }
            }
            __syncthreads();   // staging of buf^1 complete; all reads of buf done
            buf ^= 1;
        }

        // epilogue: O^T layout -> lane (g,fr): q = qt+16u+fr, d = f*16+4g+r
#pragma unroll
        for (int u = 0; u < 2; ++u) {
            const float inv = 1.0f / lrow[u];
            const size_t obase = ((size_t)nb * SEQ + qt + u * 16 + fr) * DM + h * HDIM;
#pragma unroll
            for (int f = 0; f < 8; ++f) {
                unsigned w0 = pk2bf(oacc[u][f][0] * inv, oacc[u][f][1] * inv);
                unsigned w1 = pk2bf(oacc[u][f][2] * inv, oacc[u][f][3] * inv);
                unsigned* dstp = (unsigned*)(O + obase + f * 16 + 4 * g);
                dstp[0] = w0;
                dstp[1] = w1;
            }
        }
    }
}

extern "C" void kernel_launch(void* const* d_in, const int* in_sizes, int n_in,
                              void* d_out, int out_size, void* d_ws, size_t ws_size,
                              hipStream_t stream) {
    const float* x    = (const float*)d_in[0];   // [2,2048,2048]
    const float* pos  = (const float*)d_in[1];   // [2,2048,128]
    const float* wqkv = (const float*)d_in[2];   // [6144,2048]
    const float* wo   = (const float*)d_in[3];   // [2048,2048]
    float* out = (float*)d_out;

    const size_t HBUF = (size_t)NB * NHEAD * SEQ * HDIM;  // 8Mi elems = 16MiB
    unsigned short* qb   = (unsigned short*)d_ws;         // Q; later w_o bf16
    unsigned short* kbuf = qb + HBUF;
    unsigned short* vtb  = kbuf + HBUF;
    unsigned short* obx  = vtb + HBUF;        // x_bf16 during gemm1, then attn O
    unsigned short* wqkvbf = (unsigned short*)d_out;  // 24MiB scratch in d_out
                                              // (dead before gemm_out rewrites d_out)

    // 0) pre-convert x and w_qkv to bf16
    cvt_bf16<<<dim3(2048), 256, 0, stream>>>(x, obx, 1048576, wqkv, wqkvbf, 1572864);
    // 1) QKV projection (bf16 x bf16, gload_lds) + RoPE + head scatter.
    //    1536 blocks; per XCD 6 cols x 32 rows in 2x6 chunks.
    gemm_m97<1, 6><<<dim3(1536), 256, 0, stream>>>(obx, wqkvbf, 2048, qb, kbuf, vtb, pos, nullptr);
    // 2) causal flash attention (KVBLK=64; overwrites obx with attention out)
    attn_k<<<dim3(512), 256, 0, stream>>>(qb, kbuf, vtb, obx);
    // 3) convert w_o -> bf16 into qb (dead after attn)
    cvt_bf16<<<dim3(512), 256, 0, stream>>>(wo, qb, 524288, wo, qb, 0);
    // 4) output projection (bf16 x bf16, gload_lds) -> f32 d_out.
    //    512 blocks; per XCD 2 cols x 32 rows in 2x2 chunks.
    gemm_m97<0, 2><<<dim3(512), 256, 0, stream>>>(obx, qb, 2048, nullptr, nullptr, nullptr, nullptr, out);
}